// Round 4
// baseline (22026.060 us; speedup 1.0000x reference)
//
#include <hip/hip_runtime.h>
#include <hip/hip_bf16.h>

typedef __hip_bfloat16 bf16;

#define NV_   19
#define NB_   32
#define NN_   608
#define LL_   256
#define NE_   10944
#define NROWS (NN_*LL_)      // 155648
#define NTOT  (NROWS*64)     // 9961472
#define NBC   (NROWS*16)     // 2490368

__device__ __forceinline__ float b2f(bf16 x){ return __bfloat162float(x); }
__device__ __forceinline__ bf16 f2b(float x){ return __float2bfloat16(x); }
__device__ __forceinline__ float softplusf(float x){
  return fmaxf(x, 0.f) + log1pf(expf(-fabsf(x)));
}

// ---------- GCN norm precompute ----------
__global__ void k_deg(const int* __restrict__ ei, const float* __restrict__ ew,
                      float* __restrict__ deg){
  int i = blockIdx.x*256 + threadIdx.x;
  if (i < NN_) atomicAdd(&deg[i], 1.0f);              // self loop weight 1
  if (i < NE_) atomicAdd(&deg[ei[NE_ + i]], ew[i]);
}

__global__ void k_dinv(const float* __restrict__ deg, float* __restrict__ dinv,
                       float* __restrict__ M){
  int v = blockIdx.x*256 + threadIdx.x;
  if (v >= NN_) return;
  float r = rsqrtf(fmaxf(deg[v], 1e-12f));
  dinv[v] = r;
  int b = v / NV_, lv = v - b*NV_;
  M[(b*NV_ + lv)*NV_ + lv] = r*r;                     // self-loop norm
}

__global__ void k_edges(const int* __restrict__ ei, const float* __restrict__ ew,
                        const float* __restrict__ dinv, float* __restrict__ M){
  int i = blockIdx.x*256 + threadIdx.x;
  if (i >= NE_) return;
  int s = ei[i], d = ei[NE_ + i];
  float nrm = ew[i] * dinv[s] * dinv[d];
  int b = d / NV_;
  atomicAdd(&M[(b*NV_ + (d - b*NV_))*NV_ + (s - b*NV_)], nrm);
}

// ---------- fused projections: xz, x_dbl -> u, silu(z), dtr, B, C ----------
__global__ __launch_bounds__(256)
void k_proj(const float* __restrict__ xin, const float* __restrict__ inw,
            const float* __restrict__ xpw,
            bf16* __restrict__ u, bf16* __restrict__ zs,
            float* __restrict__ dtr, bf16* __restrict__ Bm, bf16* __restrict__ Cm){
  __shared__ float inT[32*129];   // [d][e], e<128, pad 129
  __shared__ float xpT[64*35];    // [e][j], j<34, pad 35
  __shared__ float xl[4][32];
  __shared__ float xh[4][64];
  int tid = threadIdx.x;
  for (int i = tid; i < 128*32; i += 256){
    int e = i >> 5, d = i & 31;
    inT[d*129 + e] = inw[i];
  }
  for (int i = tid; i < 34*64; i += 256){
    int j = i >> 6, e = i & 63;
    xpT[e*35 + j] = xpw[i];
  }
  int w = tid >> 6, lane = tid & 63;
  int r = blockIdx.x*4 + w;                 // r = node*256 + l
  if (lane < 32) xl[w][lane] = xin[r*32 + lane];
  __syncthreads();
  float a0 = 0.f, a1 = 0.f;
  #pragma unroll
  for (int d = 0; d < 32; d++){
    float xv = xl[w][d];
    a0 = fmaf(inT[d*129 + lane], xv, a0);
    a1 = fmaf(inT[d*129 + 64 + lane], xv, a1);
  }
  int node = r >> 8, l = r & 255;
  long ob = (long)l*NN_ + node;             // t-major layout
  u[ob*64 + lane] = f2b(a0);
  zs[ob*64 + lane] = f2b(a1 / (1.f + expf(-a1)));
  xh[w][lane] = a0;
  __syncthreads();
  if (lane < 34){
    float acc = 0.f;
    #pragma unroll
    for (int e = 0; e < 64; e++) acc = fmaf(xpT[e*35 + lane], xh[w][e], acc);
    if (lane < 2)       dtr[ob*2 + lane] = acc;
    else if (lane < 18) Bm[ob*16 + lane - 2] = f2b(acc);
    else                Cm[ob*16 + lane - 18] = f2b(acc);
  }
}

// ---------- uB = gcn_vec(u_t, gB) for all t (state-independent) ----------
__global__ __launch_bounds__(256)
void k_ub(const bf16* __restrict__ u, const float* __restrict__ gBw,
          const float* __restrict__ gBb, const float* __restrict__ Mg,
          bf16* __restrict__ uB){
  __shared__ float uL[19*64];
  __shared__ float wT[64*65];     // [d][e] pad 65
  __shared__ float hL[19*64];
  __shared__ float ML[361];
  int t = blockIdx.x >> 5, b = blockIdx.x & 31;
  int tid = threadIdx.x;
  const bf16* up = u + ((long)t*NN_ + b*19)*64;
  for (int i = tid; i < 1216; i += 256) uL[i] = b2f(up[i]);
  for (int i = tid; i < 4096; i += 256){
    int e = i >> 6, d = i & 63;
    wT[d*65 + e] = gBw[i];
  }
  for (int i = tid; i < 361; i += 256) ML[i] = Mg[b*361 + i];
  __syncthreads();
  int vg = tid >> 6, e = tid & 63;
  int nv = (vg < 3) ? 5 : 4;
  float h[5];
  #pragma unroll
  for (int k = 0; k < 5; k++){
    if (k < nv){
      int v = vg + 4*k;
      float acc = 0.f;
      #pragma unroll
      for (int d = 0; d < 64; d++) acc = fmaf(wT[d*65 + e], uL[v*64 + d], acc);
      h[k] = acc;
    }
  }
  #pragma unroll
  for (int k = 0; k < 5; k++) if (k < nv) hL[(vg + 4*k)*64 + e] = h[k];
  __syncthreads();
  float bb = gBb[e];
  float acc[5];
  #pragma unroll
  for (int k = 0; k < 5; k++) acc[k] = bb;
  for (int vp = 0; vp < 19; vp++){
    float hv = hL[vp*64 + e];
    #pragma unroll
    for (int k = 0; k < 5; k++)
      if (k < nv) acc[k] = fmaf(ML[(vg + 4*k)*19 + vp], hv, acc[k]);
  }
  bf16* op = uB + ((long)t*NN_ + b*19)*64;
  #pragma unroll
  for (int k = 0; k < 5; k++)
    if (k < nv) op[(vg + 4*k)*64 + e] = f2b(acc[k]);
}

// ---------- the sequential scan: block = (batch, n-pair) ----------
// Wave-specialized: waves 0-3 ("A-team") hold gA_w row e in registers and do
// phase-A dots for BOTH halves' rows; waves 4-7 ("C-team") hold gC_w and do
// phase-C. Each thread thus keeps only 64 weight VGPRs (not 128), fitting the
// ~128-VGPR default cap for 8-wave workgroups (R2/R3: both launch_bounds
// variants capped at 128 and spilled ~34 GB/dispatch to scratch).
__global__ __launch_bounds__(512)
void k_scan(const float* __restrict__ Mg, const float* __restrict__ dtrg,
            const bf16* __restrict__ uBg, const bf16* __restrict__ Bg,
            const bf16* __restrict__ Cg,
            const float* __restrict__ gAw, const float* __restrict__ gAb,
            const float* __restrict__ gCw, const float* __restrict__ gCb,
            const float* __restrict__ Alog, const float* __restrict__ dtw,
            const float* __restrict__ dtb, bf16* __restrict__ yp)
{
  __shared__ float lds[7657];
  float* sL = lds;            // 2432: state [half][v][e]
  float* hL = lds + 2432;     // 2432
  float* yL = lds + 4864;     // 2432
  float* ML = lds + 7296;     // 361
  int b = blockIdx.x >> 3, npair = blockIdx.x & 7;
  int tid = threadIdx.x;
  int half = tid >> 8;        // 0 = A-team, 1 = C-team; also "my n-half"
  int rr = tid & 255;
  int vg = rr >> 6, e = rr & 63;
  int n = npair*2 + half;
  // stage my team's weight rows into registers via LDS scratch
  float* scr = lds + 2432;    // reuse hL+yL (4864 floats >= 4096)
  float4 W[16];
  for (int i = tid; i < 4096; i += 512) scr[i] = gAw[i];
  __syncthreads();
  if (half == 0){
    const float4* rp = (const float4*)(scr + e*64);
    #pragma unroll
    for (int d4 = 0; d4 < 16; d4++) W[d4] = rp[d4];
  }
  __syncthreads();
  for (int i = tid; i < 4096; i += 512) scr[i] = gCw[i];
  __syncthreads();
  if (half == 1){
    const float4* rp = (const float4*)(scr + e*64);
    #pragma unroll
    for (int d4 = 0; d4 < 16; d4++) W[d4] = rp[d4];
  }
  __syncthreads();
  for (int i = tid; i < 361; i += 512) ML[i] = Mg[b*361 + i];
  for (int i = tid; i < 2432; i += 512) sL[i] = 0.f;
  __syncthreads();

  float An = -expf(Alog[e*16 + n]);
  float w0 = dtw[e*2 + 0], w1 = dtw[e*2 + 1], db = dtb[e];
  float bA = gAb[e], bC = gCb[e];
  int nv = (vg < 3) ? 5 : 4;
  int nodeBase = b*19;

  for (int t = 0; t < 256; t++){
    long tbase = (long)t*NN_ + nodeBase;
    // prefetch inputs needed at the update (own n-half); latency hidden by
    // phase A (A-team computes; C-team waits at the barrier anyway)
    float dtx[5], uBv[5], Bv[5];
    #pragma unroll
    for (int k = 0; k < 5; k++){
      if (k < nv){
        long base = tbase + vg + 4*k;
        float r0 = dtrg[base*2], r1 = dtrg[base*2 + 1];
        dtx[k] = fmaf(r0, w0, fmaf(r1, w1, db));
        uBv[k] = b2f(uBg[base*64 + e]);
        Bv[k]  = b2f(Bg[base*16 + n]);
      }
    }
    // ---- phase A: A-team computes h = gA_w . s for BOTH halves ----
    if (half == 0){
      #pragma unroll
      for (int h2 = 0; h2 < 2; h2++){
        const float* sb = sL + h2*1216;
        float4 a[5];
        #pragma unroll
        for (int k = 0; k < 5; k++) a[k] = {0.f,0.f,0.f,0.f};
        #pragma unroll
        for (int d4 = 0; d4 < 16; d4++){
          float4 w4 = W[d4];
          #pragma unroll
          for (int k = 0; k < 5; k++){
            if (k < nv){
              float4 s4 = *(const float4*)(sb + (vg + 4*k)*64 + d4*4);
              a[k].x = fmaf(w4.x, s4.x, a[k].x);
              a[k].y = fmaf(w4.y, s4.y, a[k].y);
              a[k].z = fmaf(w4.z, s4.z, a[k].z);
              a[k].w = fmaf(w4.w, s4.w, a[k].w);
            }
          }
        }
        #pragma unroll
        for (int k = 0; k < 5; k++)
          if (k < nv)
            hL[h2*1216 + (vg + 4*k)*64 + e] = (a[k].x + a[k].y) + (a[k].z + a[k].w);
      }
    }
    __syncthreads();
    // ---- agg A (own half) + state update ----
    float acc[5];
    #pragma unroll
    for (int k = 0; k < 5; k++) acc[k] = bA;
    for (int vp = 0; vp < 19; vp++){
      float hv = hL[half*1216 + vp*64 + e];
      #pragma unroll
      for (int k = 0; k < 5; k++)
        if (k < nv) acc[k] = fmaf(ML[(vg + 4*k)*19 + vp], hv, acc[k]);
    }
    #pragma unroll
    for (int k = 0; k < 5; k++){
      if (k < nv){
        float dt = softplusf(dtx[k]);
        float dA = expf(dt * An);
        float snew = fmaf(acc[k], dA, uBv[k] * dt * Bv[k]);
        sL[half*1216 + (vg + 4*k)*64 + e] = snew;
      }
    }
    __syncthreads();
    // load Cv now (used after phase C; latency hidden by phase-C compute)
    float Cv[5];
    #pragma unroll
    for (int k = 0; k < 5; k++)
      if (k < nv) Cv[k] = b2f(Cg[(tbase + vg + 4*k)*16 + n]);
    // ---- phase C: C-team computes h = gC_w . s_new for BOTH halves ----
    if (half == 1){
      #pragma unroll
      for (int h2 = 0; h2 < 2; h2++){
        const float* sb = sL + h2*1216;
        float4 a[5];
        #pragma unroll
        for (int k = 0; k < 5; k++) a[k] = {0.f,0.f,0.f,0.f};
        #pragma unroll
        for (int d4 = 0; d4 < 16; d4++){
          float4 w4 = W[d4];
          #pragma unroll
          for (int k = 0; k < 5; k++){
            if (k < nv){
              float4 s4 = *(const float4*)(sb + (vg + 4*k)*64 + d4*4);
              a[k].x = fmaf(w4.x, s4.x, a[k].x);
              a[k].y = fmaf(w4.y, s4.y, a[k].y);
              a[k].z = fmaf(w4.z, s4.z, a[k].z);
              a[k].w = fmaf(w4.w, s4.w, a[k].w);
            }
          }
        }
        #pragma unroll
        for (int k = 0; k < 5; k++)
          if (k < nv)
            hL[h2*1216 + (vg + 4*k)*64 + e] = (a[k].x + a[k].y) + (a[k].z + a[k].w);
      }
    }
    __syncthreads();
    // ---- agg C (own half) + y = sC . C ----
    #pragma unroll
    for (int k = 0; k < 5; k++) acc[k] = bC;
    for (int vp = 0; vp < 19; vp++){
      float hv = hL[half*1216 + vp*64 + e];
      #pragma unroll
      for (int k = 0; k < 5; k++)
        if (k < nv) acc[k] = fmaf(ML[(vg + 4*k)*19 + vp], hv, acc[k]);
    }
    #pragma unroll
    for (int k = 0; k < 5; k++)
      if (k < nv) yL[half*1216 + (vg + 4*k)*64 + e] = acc[k] * Cv[k];
    __syncthreads();
    if (half == 0){
      #pragma unroll
      for (int k = 0; k < 5; k++){
        if (k < nv){
          int v = vg + 4*k;
          float tot = yL[v*64 + e] + yL[1216 + v*64 + e];
          yp[(((long)npair*256 + t)*NN_ + nodeBase + v)*64 + e] = f2b(tot);
        }
      }
    }
  }
}

// ---------- reduce partials, gate, out_proj ----------
__global__ __launch_bounds__(256)
void k_final(const bf16* __restrict__ yp, const bf16* __restrict__ u,
             const bf16* __restrict__ zs, const float* __restrict__ Dp,
             const float* __restrict__ ow, float* __restrict__ out)
{
  __shared__ float oT[64*33];   // [e][o] pad 33
  __shared__ float yl[4][64];
  int tid = threadIdx.x;
  for (int i = tid; i < 32*64; i += 256){
    int o = i >> 6, e = i & 63;
    oT[e*33 + o] = ow[i];
  }
  int w = tid >> 6, lane = tid & 63;
  long r = (long)blockIdx.x*4 + w;        // r = t*608 + node
  long base = r*64;
  float y = Dp[lane] * b2f(u[base + lane]);
  #pragma unroll
  for (int p = 0; p < 8; p++) y += b2f(yp[(long)p*NTOT + base + lane]);
  y *= b2f(zs[base + lane]);
  yl[w][lane] = y;
  __syncthreads();
  if (lane < 32){
    float acc = 0.f;
    #pragma unroll
    for (int e = 0; e < 64; e++) acc = fmaf(oT[e*33 + lane], yl[w][e], acc);
    int t = (int)(r / NN_), node = (int)(r - (long)t*NN_);
    out[((long)node*256 + t)*32 + lane] = acc;
  }
}

extern "C" void kernel_launch(void* const* d_in, const int* in_sizes, int n_in,
                              void* d_out, int out_size, void* d_ws, size_t ws_size,
                              hipStream_t stream)
{
  (void)in_sizes; (void)n_in; (void)out_size; (void)ws_size;
  const float* xin = (const float*)d_in[0];
  const int*   ei  = (const int*)  d_in[1];
  const float* ew  = (const float*)d_in[2];
  const float* inw = (const float*)d_in[3];
  const float* xpw = (const float*)d_in[4];
  const float* dtw = (const float*)d_in[5];
  const float* dtb = (const float*)d_in[6];
  const float* Alog= (const float*)d_in[7];
  const float* Dp  = (const float*)d_in[8];
  const float* ow  = (const float*)d_in[9];
  const float* gAw = (const float*)d_in[10];
  const float* gAb = (const float*)d_in[11];
  const float* gBw = (const float*)d_in[12];
  const float* gBb = (const float*)d_in[13];
  const float* gCw = (const float*)d_in[14];
  const float* gCb = (const float*)d_in[15];
  float* out = (float*)d_out;

  float* Mg   = (float*)d_ws;            // 11552 f32
  float* deg  = Mg + 11552;              // 608
  float* dinv = deg + 608;               // 608
  float* dtr  = dinv + 608;              // 2*NROWS f32
  bf16*  u    = (bf16*)(dtr + 2*NROWS);  // NTOT bf16
  bf16*  zs   = u + NTOT;
  bf16*  uB   = zs + NTOT;
  bf16*  Bm   = uB + NTOT;               // NBC
  bf16*  Cm   = Bm + NBC;                // NBC
  bf16*  yp   = Cm + NBC;                // 8*NTOT   (total ws ~230 MB)

  hipMemsetAsync(d_ws, 0, (11552 + 608)*sizeof(float), stream);  // M + deg
  k_deg  <<<(NE_ + 255)/256, 256, 0, stream>>>(ei, ew, deg);
  k_dinv <<<(NN_ + 255)/256, 256, 0, stream>>>(deg, dinv, Mg);
  k_edges<<<(NE_ + 255)/256, 256, 0, stream>>>(ei, ew, dinv, Mg);
  k_proj <<<NROWS/4, 256, 0, stream>>>(xin, inw, xpw, u, zs, dtr, Bm, Cm);
  k_ub   <<<LL_*NB_, 256, 0, stream>>>(u, gBw, gBb, Mg, uB);
  k_scan <<<NB_*8, 512, 0, stream>>>(Mg, dtr, uB, Bm, Cm, gAw, gAb, gCw, gCb,
                                     Alog, dtw, dtb, yp);
  k_final<<<NROWS/4, 256, 0, stream>>>(yp, u, zs, Dp, ow, out);
}

// Round 5
// 14289.940 us; speedup vs baseline: 1.5414x; 1.5414x over previous
//
#include <hip/hip_runtime.h>
#include <hip/hip_bf16.h>

typedef __hip_bfloat16 bf16;

#define NV_   19
#define NB_   32
#define NN_   608
#define LL_   256
#define NE_   10944
#define NROWS (NN_*LL_)      // 155648
#define NTOT  (NROWS*64)     // 9961472
#define NBC   (NROWS*16)     // 2490368

__device__ __forceinline__ float b2f(bf16 x){ return __bfloat162float(x); }
__device__ __forceinline__ bf16 f2b(float x){ return __float2bfloat16(x); }
__device__ __forceinline__ float softplusf(float x){
  return fmaxf(x, 0.f) + log1pf(expf(-fabsf(x)));
}

// ---------- GCN norm precompute ----------
__global__ void k_deg(const int* __restrict__ ei, const float* __restrict__ ew,
                      float* __restrict__ deg){
  int i = blockIdx.x*256 + threadIdx.x;
  if (i < NN_) atomicAdd(&deg[i], 1.0f);              // self loop weight 1
  if (i < NE_) atomicAdd(&deg[ei[NE_ + i]], ew[i]);
}

__global__ void k_dinv(const float* __restrict__ deg, float* __restrict__ dinv,
                       float* __restrict__ M){
  int v = blockIdx.x*256 + threadIdx.x;
  if (v >= NN_) return;
  float r = rsqrtf(fmaxf(deg[v], 1e-12f));
  dinv[v] = r;
  int b = v / NV_, lv = v - b*NV_;
  M[(b*NV_ + lv)*NV_ + lv] = r*r;                     // self-loop norm
}

__global__ void k_edges(const int* __restrict__ ei, const float* __restrict__ ew,
                        const float* __restrict__ dinv, float* __restrict__ M){
  int i = blockIdx.x*256 + threadIdx.x;
  if (i >= NE_) return;
  int s = ei[i], d = ei[NE_ + i];
  float nrm = ew[i] * dinv[s] * dinv[d];
  int b = d / NV_;
  atomicAdd(&M[(b*NV_ + (d - b*NV_))*NV_ + (s - b*NV_)], nrm);
}

// ---------- fused projections: xz, x_dbl -> u, silu(z), dtr, B, C ----------
__global__ __launch_bounds__(256)
void k_proj(const float* __restrict__ xin, const float* __restrict__ inw,
            const float* __restrict__ xpw,
            bf16* __restrict__ u, bf16* __restrict__ zs,
            float* __restrict__ dtr, bf16* __restrict__ Bm, bf16* __restrict__ Cm){
  __shared__ float inT[32*129];   // [d][e], e<128, pad 129
  __shared__ float xpT[64*35];    // [e][j], j<34, pad 35
  __shared__ float xl[4][32];
  __shared__ float xh[4][64];
  int tid = threadIdx.x;
  for (int i = tid; i < 128*32; i += 256){
    int e = i >> 5, d = i & 31;
    inT[d*129 + e] = inw[i];
  }
  for (int i = tid; i < 34*64; i += 256){
    int j = i >> 6, e = i & 63;
    xpT[e*35 + j] = xpw[i];
  }
  int w = tid >> 6, lane = tid & 63;
  int r = blockIdx.x*4 + w;                 // r = node*256 + l
  if (lane < 32) xl[w][lane] = xin[r*32 + lane];
  __syncthreads();
  float a0 = 0.f, a1 = 0.f;
  #pragma unroll
  for (int d = 0; d < 32; d++){
    float xv = xl[w][d];
    a0 = fmaf(inT[d*129 + lane], xv, a0);
    a1 = fmaf(inT[d*129 + 64 + lane], xv, a1);
  }
  int node = r >> 8, l = r & 255;
  long ob = (long)l*NN_ + node;             // t-major layout
  u[ob*64 + lane] = f2b(a0);
  zs[ob*64 + lane] = f2b(a1 / (1.f + expf(-a1)));
  xh[w][lane] = a0;
  __syncthreads();
  if (lane < 34){
    float acc = 0.f;
    #pragma unroll
    for (int e = 0; e < 64; e++) acc = fmaf(xpT[e*35 + lane], xh[w][e], acc);
    if (lane < 2)       dtr[ob*2 + lane] = acc;
    else if (lane < 18) Bm[ob*16 + lane - 2] = f2b(acc);
    else                Cm[ob*16 + lane - 18] = f2b(acc);
  }
}

// ---------- uB = gcn_vec(u_t, gB) for all t (state-independent) ----------
__global__ __launch_bounds__(256)
void k_ub(const bf16* __restrict__ u, const float* __restrict__ gBw,
          const float* __restrict__ gBb, const float* __restrict__ Mg,
          bf16* __restrict__ uB){
  __shared__ float uL[19*64];
  __shared__ float wT[64*65];     // [d][e] pad 65
  __shared__ float hL[19*64];
  __shared__ float ML[361];
  int t = blockIdx.x >> 5, b = blockIdx.x & 31;
  int tid = threadIdx.x;
  const bf16* up = u + ((long)t*NN_ + b*19)*64;
  for (int i = tid; i < 1216; i += 256) uL[i] = b2f(up[i]);
  for (int i = tid; i < 4096; i += 256){
    int e = i >> 6, d = i & 63;
    wT[d*65 + e] = gBw[i];
  }
  for (int i = tid; i < 361; i += 256) ML[i] = Mg[b*361 + i];
  __syncthreads();
  int vg = tid >> 6, e = tid & 63;
  int nv = (vg < 3) ? 5 : 4;
  float h[5];
  #pragma unroll
  for (int k = 0; k < 5; k++){
    if (k < nv){
      int v = vg + 4*k;
      float acc = 0.f;
      #pragma unroll
      for (int d = 0; d < 64; d++) acc = fmaf(wT[d*65 + e], uL[v*64 + d], acc);
      h[k] = acc;
    }
  }
  #pragma unroll
  for (int k = 0; k < 5; k++) if (k < nv) hL[(vg + 4*k)*64 + e] = h[k];
  __syncthreads();
  float bb = gBb[e];
  float acc[5];
  #pragma unroll
  for (int k = 0; k < 5; k++) acc[k] = bb;
  for (int vp = 0; vp < 19; vp++){
    float hv = hL[vp*64 + e];
    #pragma unroll
    for (int k = 0; k < 5; k++)
      if (k < nv) acc[k] = fmaf(ML[(vg + 4*k)*19 + vp], hv, acc[k]);
  }
  bf16* op = uB + ((long)t*NN_ + b*19)*64;
  #pragma unroll
  for (int k = 0; k < 5; k++)
    if (k < nv) op[(vg + 4*k)*64 + e] = f2b(acc[k]);
}

// ---------- the sequential scan: block = (batch, n-pair) ----------
// R2-R4 post-mortem: the compiler pins this kernel at 128 VGPRs and spills any
// register-resident weight array (~40 GB scratch traffic/dispatch). So weights
// now live in LDS in a transposed-chunk layout W4[d4][e][4]: lane e reads its
// float4 chunk at stride 16B across lanes -> conflict-free ds_read_b128, one
// read per d4 reused across 5 output rows. Per-thread live set ~75 VGPRs.
__global__ __launch_bounds__(512)
void k_scan(const float* __restrict__ Mg, const float* __restrict__ dtrg,
            const bf16* __restrict__ uBg, const bf16* __restrict__ Bg,
            const bf16* __restrict__ Cg,
            const float* __restrict__ gAw, const float* __restrict__ gAb,
            const float* __restrict__ gCw, const float* __restrict__ gCb,
            const float* __restrict__ Alog, const float* __restrict__ dtw,
            const float* __restrict__ dtb, bf16* __restrict__ yp)
{
  __shared__ float lds[9705];
  float* sL  = lds;           // 2432: state [half][v][e]
  float* hL  = lds + 2432;    // 2432
  float* yL  = lds + 4864;    // 2432
  float* WA4 = lds + 7296;    // 1024: gA_w as [d4][e][4]  (16B-aligned offset)
  float* WC4 = lds + 8320;    // 1024: gC_w as [d4][e][4]
  float* ML  = lds + 9344;    // 361
  int b = blockIdx.x >> 3, npair = blockIdx.x & 7;
  int tid = threadIdx.x;
  int half = tid >> 8;
  int rr = tid & 255;
  int vg = rr >> 6, e = rr & 63;
  int n = npair*2 + half;
  // stage weights into LDS (transposed-chunk layout), M, zero state
  for (int i = tid; i < 4096; i += 512){
    int er = i >> 6, d = i & 63;          // src row-major [e][d]
    int d4 = d >> 2, j = d & 3;
    WA4[(d4*64 + er)*4 + j] = gAw[i];
    WC4[(d4*64 + er)*4 + j] = gCw[i];
  }
  for (int i = tid; i < 361; i += 512) ML[i] = Mg[b*361 + i];
  for (int i = tid; i < 2432; i += 512) sL[i] = 0.f;
  __syncthreads();

  float An = -expf(Alog[e*16 + n]);
  float w0 = dtw[e*2 + 0], w1 = dtw[e*2 + 1], db = dtb[e];
  float bA = gAb[e], bC = gCb[e];
  int nv = (vg < 3) ? 5 : 4;
  int nodeBase = b*19;

  for (int t = 0; t < 256; t++){
    long tbase = (long)t*NN_ + nodeBase;
    // prefetch this step's update inputs (latency hidden by phase A)
    float dtx[5], uBv[5], Bv[5];
    #pragma unroll
    for (int k = 0; k < 5; k++){
      if (k < nv){
        long base = tbase + vg + 4*k;
        float r0 = dtrg[base*2], r1 = dtrg[base*2 + 1];
        dtx[k] = fmaf(r0, w0, fmaf(r1, w1, db));
        uBv[k] = b2f(uBg[base*64 + e]);
        Bv[k]  = b2f(Bg[base*16 + n]);
      }
    }
    // ---- phase A: h[v][e] = gA_w[e] . s[half][v] ----
    {
      float4 a[5];
      #pragma unroll
      for (int k = 0; k < 5; k++) a[k] = {0.f,0.f,0.f,0.f};
      #pragma unroll
      for (int d4 = 0; d4 < 16; d4++){
        float4 w4 = *(const float4*)(WA4 + (d4*64 + e)*4);
        #pragma unroll
        for (int k = 0; k < 5; k++){
          if (k < nv){
            float4 s4 = *(const float4*)(sL + (half*19 + vg + 4*k)*64 + d4*4);
            a[k].x = fmaf(w4.x, s4.x, a[k].x);
            a[k].y = fmaf(w4.y, s4.y, a[k].y);
            a[k].z = fmaf(w4.z, s4.z, a[k].z);
            a[k].w = fmaf(w4.w, s4.w, a[k].w);
          }
        }
      }
      #pragma unroll
      for (int k = 0; k < 5; k++)
        if (k < nv)
          hL[half*1216 + (vg + 4*k)*64 + e] = (a[k].x + a[k].y) + (a[k].z + a[k].w);
    }
    __syncthreads();
    // ---- agg A (M broadcast) + state update ----
    float acc[5];
    #pragma unroll
    for (int k = 0; k < 5; k++) acc[k] = bA;
    for (int vp = 0; vp < 19; vp++){
      float hv = hL[half*1216 + vp*64 + e];
      #pragma unroll
      for (int k = 0; k < 5; k++)
        if (k < nv) acc[k] = fmaf(ML[(vg + 4*k)*19 + vp], hv, acc[k]);
    }
    #pragma unroll
    for (int k = 0; k < 5; k++){
      if (k < nv){
        float dt = softplusf(dtx[k]);
        float dA = expf(dt * An);
        float snew = fmaf(acc[k], dA, uBv[k] * dt * Bv[k]);
        sL[half*1216 + (vg + 4*k)*64 + e] = snew;
      }
    }
    __syncthreads();
    // load Cv now (used after phase C; latency hidden by phase-C compute)
    float Cv[5];
    #pragma unroll
    for (int k = 0; k < 5; k++)
      if (k < nv) Cv[k] = b2f(Cg[(tbase + vg + 4*k)*16 + n]);
    // ---- phase C: h = gC_w . s_new ----
    {
      float4 a[5];
      #pragma unroll
      for (int k = 0; k < 5; k++) a[k] = {0.f,0.f,0.f,0.f};
      #pragma unroll
      for (int d4 = 0; d4 < 16; d4++){
        float4 w4 = *(const float4*)(WC4 + (d4*64 + e)*4);
        #pragma unroll
        for (int k = 0; k < 5; k++){
          if (k < nv){
            float4 s4 = *(const float4*)(sL + (half*19 + vg + 4*k)*64 + d4*4);
            a[k].x = fmaf(w4.x, s4.x, a[k].x);
            a[k].y = fmaf(w4.y, s4.y, a[k].y);
            a[k].z = fmaf(w4.z, s4.z, a[k].z);
            a[k].w = fmaf(w4.w, s4.w, a[k].w);
          }
        }
      }
      #pragma unroll
      for (int k = 0; k < 5; k++)
        if (k < nv)
          hL[half*1216 + (vg + 4*k)*64 + e] = (a[k].x + a[k].y) + (a[k].z + a[k].w);
    }
    __syncthreads();
    // ---- agg C + y = sC . C ----
    #pragma unroll
    for (int k = 0; k < 5; k++) acc[k] = bC;
    for (int vp = 0; vp < 19; vp++){
      float hv = hL[half*1216 + vp*64 + e];
      #pragma unroll
      for (int k = 0; k < 5; k++)
        if (k < nv) acc[k] = fmaf(ML[(vg + 4*k)*19 + vp], hv, acc[k]);
    }
    #pragma unroll
    for (int k = 0; k < 5; k++)
      if (k < nv) yL[half*1216 + (vg + 4*k)*64 + e] = acc[k] * Cv[k];
    __syncthreads();
    if (half == 0){
      #pragma unroll
      for (int k = 0; k < 5; k++){
        if (k < nv){
          int v = vg + 4*k;
          float tot = yL[v*64 + e] + yL[1216 + v*64 + e];
          yp[(((long)npair*256 + t)*NN_ + nodeBase + v)*64 + e] = f2b(tot);
        }
      }
    }
  }
}

// ---------- reduce partials, gate, out_proj ----------
__global__ __launch_bounds__(256)
void k_final(const bf16* __restrict__ yp, const bf16* __restrict__ u,
             const bf16* __restrict__ zs, const float* __restrict__ Dp,
             const float* __restrict__ ow, float* __restrict__ out)
{
  __shared__ float oT[64*33];   // [e][o] pad 33
  __shared__ float yl[4][64];
  int tid = threadIdx.x;
  for (int i = tid; i < 32*64; i += 256){
    int o = i >> 6, e = i & 63;
    oT[e*33 + o] = ow[i];
  }
  int w = tid >> 6, lane = tid & 63;
  long r = (long)blockIdx.x*4 + w;        // r = t*608 + node
  long base = r*64;
  float y = Dp[lane] * b2f(u[base + lane]);
  #pragma unroll
  for (int p = 0; p < 8; p++) y += b2f(yp[(long)p*NTOT + base + lane]);
  y *= b2f(zs[base + lane]);
  yl[w][lane] = y;
  __syncthreads();
  if (lane < 32){
    float acc = 0.f;
    #pragma unroll
    for (int e = 0; e < 64; e++) acc = fmaf(oT[e*33 + lane], yl[w][e], acc);
    int t = (int)(r / NN_), node = (int)(r - (long)t*NN_);
    out[((long)node*256 + t)*32 + lane] = acc;
  }
}

extern "C" void kernel_launch(void* const* d_in, const int* in_sizes, int n_in,
                              void* d_out, int out_size, void* d_ws, size_t ws_size,
                              hipStream_t stream)
{
  (void)in_sizes; (void)n_in; (void)out_size; (void)ws_size;
  const float* xin = (const float*)d_in[0];
  const int*   ei  = (const int*)  d_in[1];
  const float* ew  = (const float*)d_in[2];
  const float* inw = (const float*)d_in[3];
  const float* xpw = (const float*)d_in[4];
  const float* dtw = (const float*)d_in[5];
  const float* dtb = (const float*)d_in[6];
  const float* Alog= (const float*)d_in[7];
  const float* Dp  = (const float*)d_in[8];
  const float* ow  = (const float*)d_in[9];
  const float* gAw = (const float*)d_in[10];
  const float* gAb = (const float*)d_in[11];
  const float* gBw = (const float*)d_in[12];
  const float* gBb = (const float*)d_in[13];
  const float* gCw = (const float*)d_in[14];
  const float* gCb = (const float*)d_in[15];
  float* out = (float*)d_out;

  float* Mg   = (float*)d_ws;            // 11552 f32
  float* deg  = Mg + 11552;              // 608
  float* dinv = deg + 608;               // 608
  float* dtr  = dinv + 608;              // 2*NROWS f32
  bf16*  u    = (bf16*)(dtr + 2*NROWS);  // NTOT bf16
  bf16*  zs   = u + NTOT;
  bf16*  uB   = zs + NTOT;
  bf16*  Bm   = uB + NTOT;               // NBC
  bf16*  Cm   = Bm + NBC;                // NBC
  bf16*  yp   = Cm + NBC;                // 8*NTOT   (total ws ~230 MB)

  hipMemsetAsync(d_ws, 0, (11552 + 608)*sizeof(float), stream);  // M + deg
  k_deg  <<<(NE_ + 255)/256, 256, 0, stream>>>(ei, ew, deg);
  k_dinv <<<(NN_ + 255)/256, 256, 0, stream>>>(deg, dinv, Mg);
  k_edges<<<(NE_ + 255)/256, 256, 0, stream>>>(ei, ew, dinv, Mg);
  k_proj <<<NROWS/4, 256, 0, stream>>>(xin, inw, xpw, u, zs, dtr, Bm, Cm);
  k_ub   <<<LL_*NB_, 256, 0, stream>>>(u, gBw, gBb, Mg, uB);
  k_scan <<<NB_*8, 512, 0, stream>>>(Mg, dtr, uB, Bm, Cm, gAw, gAb, gCw, gCb,
                                     Alog, dtw, dtb, yp);
  k_final<<<NROWS/4, 256, 0, stream>>>(yp, u, zs, Dp, ow, out);
}

// Round 6
// 2206.644 us; speedup vs baseline: 9.9817x; 6.4759x over previous
//
#include <hip/hip_runtime.h>
#include <hip/hip_bf16.h>

typedef __hip_bfloat16 bf16;

#define NV_   19
#define NB_   32
#define NN_   608
#define LL_   256
#define NE_   10944
#define NROWS (NN_*LL_)      // 155648
#define NTOT  (NROWS*64)     // 9961472
#define NBC   (NROWS*16)     // 2490368

__device__ __forceinline__ float b2f(bf16 x){ return __bfloat162float(x); }
__device__ __forceinline__ bf16 f2b(float x){ return __float2bfloat16(x); }
__device__ __forceinline__ float softplusf(float x){
  return fmaxf(x, 0.f) + log1pf(expf(-fabsf(x)));
}

// ---------- GCN norm precompute ----------
__global__ void k_deg(const int* __restrict__ ei, const float* __restrict__ ew,
                      float* __restrict__ deg){
  int i = blockIdx.x*256 + threadIdx.x;
  if (i < NN_) atomicAdd(&deg[i], 1.0f);              // self loop weight 1
  if (i < NE_) atomicAdd(&deg[ei[NE_ + i]], ew[i]);
}

__global__ void k_dinv(const float* __restrict__ deg, float* __restrict__ dinv,
                       float* __restrict__ M){
  int v = blockIdx.x*256 + threadIdx.x;
  if (v >= NN_) return;
  float r = rsqrtf(fmaxf(deg[v], 1e-12f));
  dinv[v] = r;
  int b = v / NV_, lv = v - b*NV_;
  M[(b*NV_ + lv)*NV_ + lv] = r*r;                     // self-loop norm
}

__global__ void k_edges(const int* __restrict__ ei, const float* __restrict__ ew,
                        const float* __restrict__ dinv, float* __restrict__ M){
  int i = blockIdx.x*256 + threadIdx.x;
  if (i >= NE_) return;
  int s = ei[i], d = ei[NE_ + i];
  float nrm = ew[i] * dinv[s] * dinv[d];
  int b = d / NV_;
  atomicAdd(&M[(b*NV_ + (d - b*NV_))*NV_ + (s - b*NV_)], nrm);
}

// ---------- fused projections: xz, x_dbl -> u, silu(z), dtr, B, C ----------
__global__ __launch_bounds__(256)
void k_proj(const float* __restrict__ xin, const float* __restrict__ inw,
            const float* __restrict__ xpw,
            bf16* __restrict__ u, bf16* __restrict__ zs,
            float* __restrict__ dtr, bf16* __restrict__ Bm, bf16* __restrict__ Cm){
  __shared__ float inT[32*129];   // [d][e], e<128, pad 129
  __shared__ float xpT[64*35];    // [e][j], j<34, pad 35
  __shared__ float xl[4][32];
  __shared__ float xh[4][64];
  int tid = threadIdx.x;
  for (int i = tid; i < 128*32; i += 256){
    int e = i >> 5, d = i & 31;
    inT[d*129 + e] = inw[i];
  }
  for (int i = tid; i < 34*64; i += 256){
    int j = i >> 6, e = i & 63;
    xpT[e*35 + j] = xpw[i];
  }
  int w = tid >> 6, lane = tid & 63;
  int r = blockIdx.x*4 + w;                 // r = node*256 + l
  if (lane < 32) xl[w][lane] = xin[r*32 + lane];
  __syncthreads();
  float a0 = 0.f, a1 = 0.f;
  #pragma unroll
  for (int d = 0; d < 32; d++){
    float xv = xl[w][d];
    a0 = fmaf(inT[d*129 + lane], xv, a0);
    a1 = fmaf(inT[d*129 + 64 + lane], xv, a1);
  }
  int node = r >> 8, l = r & 255;
  long ob = (long)l*NN_ + node;             // t-major layout
  u[ob*64 + lane] = f2b(a0);
  zs[ob*64 + lane] = f2b(a1 / (1.f + expf(-a1)));
  xh[w][lane] = a0;
  __syncthreads();
  if (lane < 34){
    float acc = 0.f;
    #pragma unroll
    for (int e = 0; e < 64; e++) acc = fmaf(xpT[e*35 + lane], xh[w][e], acc);
    if (lane < 2)       dtr[ob*2 + lane] = acc;
    else if (lane < 18) Bm[ob*16 + lane - 2] = f2b(acc);
    else                Cm[ob*16 + lane - 18] = f2b(acc);
  }
}

// ---------- uB = gcn_vec(u_t, gB) for all t (state-independent) ----------
// Guard-free version: rows padded 19->20, dummy row19 clamps loads to row18
// and is excluded from aggregation via zero-padded MLP, skipped on store.
__global__ __launch_bounds__(256)
void k_ub(const bf16* __restrict__ u, const float* __restrict__ gBw,
          const float* __restrict__ gBb, const float* __restrict__ Mg,
          bf16* __restrict__ uB){
  __shared__ float uL[19*64];
  __shared__ float wT[64*65];     // [d][e] pad 65
  __shared__ float hL[20*64];
  __shared__ float MLP[640];      // [vp][vg*8+k] = M_pad[vg+4k][vp]
  int t = blockIdx.x >> 5, b = blockIdx.x & 31;
  int tid = threadIdx.x;
  const bf16* up = u + ((long)t*NN_ + b*19)*64;
  for (int i = tid; i < 1216; i += 256) uL[i] = b2f(up[i]);
  for (int i = tid; i < 4096; i += 256){
    int e = i >> 6, d = i & 63;
    wT[d*65 + e] = gBw[i];
  }
  for (int i = tid; i < 640; i += 256){
    int vp = i >> 5, c = i & 31, g = c >> 3, k = c & 7;
    int v = g + 4*k;
    MLP[i] = (k < 5 && vp < 19 && v < 19) ? Mg[b*361 + v*19 + vp] : 0.f;
  }
  __syncthreads();
  int vg = tid >> 6, e = tid & 63;
  int v0 = vg, v1 = vg+4, v2 = vg+8, v3 = vg+12, v4 = vg+16;
  int v4c = (vg == 3) ? 18 : v4;            // clamped for loads
  float h0=0.f,h1=0.f,h2=0.f,h3=0.f,h4=0.f;
  #pragma unroll
  for (int d = 0; d < 64; d++){
    float wv = wT[d*65 + e];
    h0 = fmaf(wv, uL[v0*64 + d], h0);
    h1 = fmaf(wv, uL[v1*64 + d], h1);
    h2 = fmaf(wv, uL[v2*64 + d], h2);
    h3 = fmaf(wv, uL[v3*64 + d], h3);
    h4 = fmaf(wv, uL[v4c*64 + d], h4);
  }
  hL[v0*64 + e] = h0; hL[v1*64 + e] = h1; hL[v2*64 + e] = h2;
  hL[v3*64 + e] = h3; hL[v4*64 + e] = h4;
  __syncthreads();
  float bb = gBb[e];
  float acc0=bb, acc1=bb, acc2=bb, acc3=bb, acc4=bb;
  const float* mlb = MLP + vg*8;
  #pragma unroll
  for (int vp = 0; vp < 20; vp++){
    float hv = hL[vp*64 + e];
    float4 m4 = *(const float4*)(mlb + vp*32);
    float  m5 = mlb[vp*32 + 4];
    acc0 = fmaf(m4.x, hv, acc0); acc1 = fmaf(m4.y, hv, acc1);
    acc2 = fmaf(m4.z, hv, acc2); acc3 = fmaf(m4.w, hv, acc3);
    acc4 = fmaf(m5,  hv, acc4);
  }
  bf16* op = uB + ((long)t*NN_ + b*19)*64;
  op[v0*64 + e] = f2b(acc0);
  op[v1*64 + e] = f2b(acc1);
  op[v2*64 + e] = f2b(acc2);
  op[v3*64 + e] = f2b(acc3);
  if (vg != 3) op[v4*64 + e] = f2b(acc4);
}

// ---------- the sequential scan: block = (batch, n-pair) ----------
// R2-R5 post-mortem: guarded per-thread arrays were never SROA-promoted ->
// allocas in scratch -> ~1 KB/thread/step of HBM traffic. This version is
// guard-free (rows padded 19->20; dummy row clamps loads, zero-padded M,
// wave-uniform store guards only) and uses only named scalars in the t-loop.
__global__ __launch_bounds__(512)
void k_scan(const float* __restrict__ Mg, const float* __restrict__ dtrg,
            const bf16* __restrict__ uBg, const bf16* __restrict__ Bg,
            const bf16* __restrict__ Cg,
            const float* __restrict__ gAw, const float* __restrict__ gAb,
            const float* __restrict__ gCw, const float* __restrict__ gCb,
            const float* __restrict__ Alog, const float* __restrict__ dtw,
            const float* __restrict__ dtb, bf16* __restrict__ yp)
{
  __shared__ float lds[10368];
  float* sL  = lds;            // 2560: state [half][v<20][e]
  float* hL  = lds + 2560;     // 2560
  float* yL  = lds + 5120;     // 2560
  float* WA4 = lds + 7680;     // 1024: gA_w as [d4][e][4]
  float* WC4 = lds + 8704;     // 1024: gC_w as [d4][e][4]
  float* MLP = lds + 9728;     // 640: [vp][vg*8+k] = M_pad[vg+4k][vp]
  int b = blockIdx.x >> 3, npair = blockIdx.x & 7;
  int tid = threadIdx.x;
  int half = tid >> 8;
  int rr = tid & 255;
  int vg = rr >> 6, e = rr & 63;
  int n = npair*2 + half;
  for (int i = tid; i < 4096; i += 512){
    int er = i >> 6, d = i & 63, d4 = d >> 2, j = d & 3;
    WA4[(d4*64 + er)*4 + j] = gAw[i];
    WC4[(d4*64 + er)*4 + j] = gCw[i];
  }
  for (int i = tid; i < 640; i += 512){
    int vp = i >> 5, c = i & 31, g = c >> 3, k = c & 7;
    int v = g + 4*k;
    MLP[i] = (k < 5 && vp < 19 && v < 19) ? Mg[b*361 + v*19 + vp] : 0.f;
  }
  for (int i = tid; i < 5120; i += 512) sL[i] = 0.f;   // also zeroes hL
  __syncthreads();

  float An = -expf(Alog[e*16 + n]);
  float w0 = dtw[e*2 + 0], w1 = dtw[e*2 + 1], db = dtb[e];
  float bA = gAb[e], bC = gCb[e];
  int nodeBase = b*19;
  const int v0 = vg, v1 = vg+4, v2 = vg+8, v3 = vg+12, v4 = vg+16;
  const int v4c = (vg == 3) ? 18 : v4;     // clamped row for loads
  const float* sb  = sL + half*1280 + vg*64;
  float*       sw  = sL + half*1280 + vg*64 + e;
  float*       hw  = hL + half*1280 + vg*64 + e;
  const float* hb  = hL + half*1280 + e;
  const float* mlb = MLP + vg*8;

  for (int t = 0; t < 256; t++){
    long tbase = (long)t*NN_ + nodeBase;
    long b0 = tbase + v0, b1 = tbase + v1, b2 = tbase + v2,
         b3 = tbase + v3, b4 = tbase + v4c;
    // prefetch this step's inputs (named scalars; consumed after phase A)
    float dt0 = fmaf(dtrg[b0*2], w0, fmaf(dtrg[b0*2+1], w1, db));
    float dt1 = fmaf(dtrg[b1*2], w0, fmaf(dtrg[b1*2+1], w1, db));
    float dt2 = fmaf(dtrg[b2*2], w0, fmaf(dtrg[b2*2+1], w1, db));
    float dt3 = fmaf(dtrg[b3*2], w0, fmaf(dtrg[b3*2+1], w1, db));
    float dt4 = fmaf(dtrg[b4*2], w0, fmaf(dtrg[b4*2+1], w1, db));
    float uB0 = b2f(uBg[b0*64 + e]), uB1 = b2f(uBg[b1*64 + e]);
    float uB2 = b2f(uBg[b2*64 + e]), uB3 = b2f(uBg[b3*64 + e]);
    float uB4 = b2f(uBg[b4*64 + e]);
    float Bv0 = b2f(Bg[b0*16 + n]), Bv1 = b2f(Bg[b1*16 + n]);
    float Bv2 = b2f(Bg[b2*16 + n]), Bv3 = b2f(Bg[b3*16 + n]);
    float Bv4 = b2f(Bg[b4*16 + n]);
    float Cv0 = b2f(Cg[b0*16 + n]), Cv1 = b2f(Cg[b1*16 + n]);
    float Cv2 = b2f(Cg[b2*16 + n]), Cv3 = b2f(Cg[b3*16 + n]);
    float Cv4 = b2f(Cg[b4*16 + n]);
    // ---- phase A: h[v][e] = gA_w[e] . s[half][v] ----
    {
      float4 a0={0,0,0,0}, a1=a0, a2=a0, a3=a0, a4=a0;
      #pragma unroll
      for (int d4 = 0; d4 < 16; d4++){
        float4 w4 = *(const float4*)(WA4 + d4*256 + e*4);
        float4 s0 = *(const float4*)(sb + d4*4);
        float4 s1 = *(const float4*)(sb + 256 + d4*4);
        float4 s2 = *(const float4*)(sb + 512 + d4*4);
        float4 s3 = *(const float4*)(sb + 768 + d4*4);
        float4 s4 = *(const float4*)(sb + 1024 + d4*4);
        a0.x=fmaf(w4.x,s0.x,a0.x); a0.y=fmaf(w4.y,s0.y,a0.y); a0.z=fmaf(w4.z,s0.z,a0.z); a0.w=fmaf(w4.w,s0.w,a0.w);
        a1.x=fmaf(w4.x,s1.x,a1.x); a1.y=fmaf(w4.y,s1.y,a1.y); a1.z=fmaf(w4.z,s1.z,a1.z); a1.w=fmaf(w4.w,s1.w,a1.w);
        a2.x=fmaf(w4.x,s2.x,a2.x); a2.y=fmaf(w4.y,s2.y,a2.y); a2.z=fmaf(w4.z,s2.z,a2.z); a2.w=fmaf(w4.w,s2.w,a2.w);
        a3.x=fmaf(w4.x,s3.x,a3.x); a3.y=fmaf(w4.y,s3.y,a3.y); a3.z=fmaf(w4.z,s3.z,a3.z); a3.w=fmaf(w4.w,s3.w,a3.w);
        a4.x=fmaf(w4.x,s4.x,a4.x); a4.y=fmaf(w4.y,s4.y,a4.y); a4.z=fmaf(w4.z,s4.z,a4.z); a4.w=fmaf(w4.w,s4.w,a4.w);
      }
      hw[0]    = (a0.x+a0.y)+(a0.z+a0.w);
      hw[256]  = (a1.x+a1.y)+(a1.z+a1.w);
      hw[512]  = (a2.x+a2.y)+(a2.z+a2.w);
      hw[768]  = (a3.x+a3.y)+(a3.z+a3.w);
      hw[1024] = (a4.x+a4.y)+(a4.z+a4.w);
    }
    __syncthreads();
    // ---- agg A (zero-padded M) + state update ----
    {
      float acc0=bA, acc1=bA, acc2=bA, acc3=bA, acc4=bA;
      #pragma unroll
      for (int vp = 0; vp < 20; vp++){
        float hv = hb[vp*64];
        float4 m4 = *(const float4*)(mlb + vp*32);
        float  m5 = mlb[vp*32 + 4];
        acc0 = fmaf(m4.x, hv, acc0); acc1 = fmaf(m4.y, hv, acc1);
        acc2 = fmaf(m4.z, hv, acc2); acc3 = fmaf(m4.w, hv, acc3);
        acc4 = fmaf(m5,  hv, acc4);
      }
      float sp0 = softplusf(dt0), sp1 = softplusf(dt1), sp2 = softplusf(dt2);
      float sp3 = softplusf(dt3), sp4 = softplusf(dt4);
      sw[0]    = fmaf(acc0, expf(sp0*An), uB0*sp0*Bv0);
      sw[256]  = fmaf(acc1, expf(sp1*An), uB1*sp1*Bv1);
      sw[512]  = fmaf(acc2, expf(sp2*An), uB2*sp2*Bv2);
      sw[768]  = fmaf(acc3, expf(sp3*An), uB3*sp3*Bv3);
      sw[1024] = fmaf(acc4, expf(sp4*An), uB4*sp4*Bv4);
    }
    __syncthreads();
    // ---- phase C: h = gC_w . s_new ----
    {
      float4 a0={0,0,0,0}, a1=a0, a2=a0, a3=a0, a4=a0;
      #pragma unroll
      for (int d4 = 0; d4 < 16; d4++){
        float4 w4 = *(const float4*)(WC4 + d4*256 + e*4);
        float4 s0 = *(const float4*)(sb + d4*4);
        float4 s1 = *(const float4*)(sb + 256 + d4*4);
        float4 s2 = *(const float4*)(sb + 512 + d4*4);
        float4 s3 = *(const float4*)(sb + 768 + d4*4);
        float4 s4 = *(const float4*)(sb + 1024 + d4*4);
        a0.x=fmaf(w4.x,s0.x,a0.x); a0.y=fmaf(w4.y,s0.y,a0.y); a0.z=fmaf(w4.z,s0.z,a0.z); a0.w=fmaf(w4.w,s0.w,a0.w);
        a1.x=fmaf(w4.x,s1.x,a1.x); a1.y=fmaf(w4.y,s1.y,a1.y); a1.z=fmaf(w4.z,s1.z,a1.z); a1.w=fmaf(w4.w,s1.w,a1.w);
        a2.x=fmaf(w4.x,s2.x,a2.x); a2.y=fmaf(w4.y,s2.y,a2.y); a2.z=fmaf(w4.z,s2.z,a2.z); a2.w=fmaf(w4.w,s2.w,a2.w);
        a3.x=fmaf(w4.x,s3.x,a3.x); a3.y=fmaf(w4.y,s3.y,a3.y); a3.z=fmaf(w4.z,s3.z,a3.z); a3.w=fmaf(w4.w,s3.w,a3.w);
        a4.x=fmaf(w4.x,s4.x,a4.x); a4.y=fmaf(w4.y,s4.y,a4.y); a4.z=fmaf(w4.z,s4.z,a4.z); a4.w=fmaf(w4.w,s4.w,a4.w);
      }
      hw[0]    = (a0.x+a0.y)+(a0.z+a0.w);
      hw[256]  = (a1.x+a1.y)+(a1.z+a1.w);
      hw[512]  = (a2.x+a2.y)+(a2.z+a2.w);
      hw[768]  = (a3.x+a3.y)+(a3.z+a3.w);
      hw[1024] = (a4.x+a4.y)+(a4.z+a4.w);
    }
    __syncthreads();
    // ---- agg C + y = sC . C ----
    {
      float acc0=bC, acc1=bC, acc2=bC, acc3=bC, acc4=bC;
      #pragma unroll
      for (int vp = 0; vp < 20; vp++){
        float hv = hb[vp*64];
        float4 m4 = *(const float4*)(mlb + vp*32);
        float  m5 = mlb[vp*32 + 4];
        acc0 = fmaf(m4.x, hv, acc0); acc1 = fmaf(m4.y, hv, acc1);
        acc2 = fmaf(m4.z, hv, acc2); acc3 = fmaf(m4.w, hv, acc3);
        acc4 = fmaf(m5,  hv, acc4);
      }
      float* yw = yL + half*1280 + vg*64 + e;
      yw[0]    = acc0 * Cv0;
      yw[256]  = acc1 * Cv1;
      yw[512]  = acc2 * Cv2;
      yw[768]  = acc3 * Cv3;
      yw[1024] = acc4 * Cv4;
    }
    __syncthreads();
    if (half == 0){
      long ob = ((long)(npair*256 + t)*NN_ + nodeBase)*64 + e;
      const float* yr = yL + vg*64 + e;
      yp[ob + v0*64] = f2b(yr[0]    + yr[1280]);
      yp[ob + v1*64] = f2b(yr[256]  + yr[1536]);
      yp[ob + v2*64] = f2b(yr[512]  + yr[1792]);
      yp[ob + v3*64] = f2b(yr[768]  + yr[2048]);
      if (vg != 3) yp[ob + v4*64] = f2b(yr[1024] + yr[2304]);
    }
  }
}

// ---------- reduce partials, gate, out_proj ----------
__global__ __launch_bounds__(256)
void k_final(const bf16* __restrict__ yp, const bf16* __restrict__ u,
             const bf16* __restrict__ zs, const float* __restrict__ Dp,
             const float* __restrict__ ow, float* __restrict__ out)
{
  __shared__ float oT[64*33];   // [e][o] pad 33
  __shared__ float yl[4][64];
  int tid = threadIdx.x;
  for (int i = tid; i < 32*64; i += 256){
    int o = i >> 6, e = i & 63;
    oT[e*33 + o] = ow[i];
  }
  int w = tid >> 6, lane = tid & 63;
  long r = (long)blockIdx.x*4 + w;        // r = t*608 + node
  long base = r*64;
  float y = Dp[lane] * b2f(u[base + lane]);
  #pragma unroll
  for (int p = 0; p < 8; p++) y += b2f(yp[(long)p*NTOT + base + lane]);
  y *= b2f(zs[base + lane]);
  yl[w][lane] = y;
  __syncthreads();
  if (lane < 32){
    float acc = 0.f;
    #pragma unroll
    for (int e = 0; e < 64; e++) acc = fmaf(oT[e*33 + lane], yl[w][e], acc);
    int t = (int)(r / NN_), node = (int)(r - (long)t*NN_);
    out[((long)node*256 + t)*32 + lane] = acc;
  }
}

extern "C" void kernel_launch(void* const* d_in, const int* in_sizes, int n_in,
                              void* d_out, int out_size, void* d_ws, size_t ws_size,
                              hipStream_t stream)
{
  (void)in_sizes; (void)n_in; (void)out_size; (void)ws_size;
  const float* xin = (const float*)d_in[0];
  const int*   ei  = (const int*)  d_in[1];
  const float* ew  = (const float*)d_in[2];
  const float* inw = (const float*)d_in[3];
  const float* xpw = (const float*)d_in[4];
  const float* dtw = (const float*)d_in[5];
  const float* dtb = (const float*)d_in[6];
  const float* Alog= (const float*)d_in[7];
  const float* Dp  = (const float*)d_in[8];
  const float* ow  = (const float*)d_in[9];
  const float* gAw = (const float*)d_in[10];
  const float* gAb = (const float*)d_in[11];
  const float* gBw = (const float*)d_in[12];
  const float* gBb = (const float*)d_in[13];
  const float* gCw = (const float*)d_in[14];
  const float* gCb = (const float*)d_in[15];
  float* out = (float*)d_out;

  float* Mg   = (float*)d_ws;            // 11552 f32
  float* deg  = Mg + 11552;              // 608
  float* dinv = deg + 608;               // 608
  float* dtr  = dinv + 608;              // 2*NROWS f32
  bf16*  u    = (bf16*)(dtr + 2*NROWS);  // NTOT bf16
  bf16*  zs   = u + NTOT;
  bf16*  uB   = zs + NTOT;
  bf16*  Bm   = uB + NTOT;               // NBC
  bf16*  Cm   = Bm + NBC;                // NBC
  bf16*  yp   = Cm + NBC;                // 8*NTOT   (total ws ~230 MB)

  hipMemsetAsync(d_ws, 0, (11552 + 608)*sizeof(float), stream);  // M + deg
  k_deg  <<<(NE_ + 255)/256, 256, 0, stream>>>(ei, ew, deg);
  k_dinv <<<(NN_ + 255)/256, 256, 0, stream>>>(deg, dinv, Mg);
  k_edges<<<(NE_ + 255)/256, 256, 0, stream>>>(ei, ew, dinv, Mg);
  k_proj <<<NROWS/4, 256, 0, stream>>>(xin, inw, xpw, u, zs, dtr, Bm, Cm);
  k_ub   <<<LL_*NB_, 256, 0, stream>>>(u, gBw, gBb, Mg, uB);
  k_scan <<<NB_*8, 512, 0, stream>>>(Mg, dtr, uB, Bm, Cm, gAw, gAb, gCw, gCb,
                                     Alog, dtw, dtb, yp);
  k_final<<<NROWS/4, 256, 0, stream>>>(yp, u, zs, Dp, ow, out);
}

// Round 7
// 995.423 us; speedup vs baseline: 22.1273x; 2.2168x over previous
//
#include <hip/hip_runtime.h>
#include <hip/hip_bf16.h>

typedef __hip_bfloat16 bf16;
typedef __attribute__((ext_vector_type(8))) short bf16x8;
typedef __attribute__((ext_vector_type(4))) float f32x4;

#define NV_   19
#define NB_   32
#define NN_   608
#define LL_   256
#define NE_   10944
#define NROWS (NN_*LL_)      // 155648
#define NTOT  (NROWS*64)     // 9961472
#define NBC   (NROWS*16)     // 2490368

__device__ __forceinline__ float b2f(bf16 x){ return __bfloat162float(x); }
__device__ __forceinline__ bf16 f2b(float x){ return __float2bfloat16(x); }
__device__ __forceinline__ unsigned short f2bs(float x){
  union { float f; unsigned u; } c; c.f = x;
  unsigned r = c.u + 0x7FFFu + ((c.u >> 16) & 1u);
  return (unsigned short)(r >> 16);
}
__device__ __forceinline__ float busf(unsigned short s){
  union { unsigned u; float f; } c; c.u = ((unsigned)s) << 16; return c.f;
}
__device__ __forceinline__ unsigned pk2(float a, float b){
  return (unsigned)f2bs(a) | ((unsigned)f2bs(b) << 16);
}
__device__ __forceinline__ float fsoftplus(float x){
  return fmaxf(x, 0.f) + __logf(1.f + __expf(-fabsf(x)));
}

// ---------- GCN norm precompute ----------
__global__ void k_deg(const int* __restrict__ ei, const float* __restrict__ ew,
                      float* __restrict__ deg){
  int i = blockIdx.x*256 + threadIdx.x;
  if (i < NN_) atomicAdd(&deg[i], 1.0f);              // self loop weight 1
  if (i < NE_) atomicAdd(&deg[ei[NE_ + i]], ew[i]);
}

__global__ void k_dinv(const float* __restrict__ deg, float* __restrict__ dinv,
                       float* __restrict__ M){
  int v = blockIdx.x*256 + threadIdx.x;
  if (v >= NN_) return;
  float r = rsqrtf(fmaxf(deg[v], 1e-12f));
  dinv[v] = r;
  int b = v / NV_, lv = v - b*NV_;
  M[(b*NV_ + lv)*NV_ + lv] = r*r;                     // self-loop norm
}

__global__ void k_edges(const int* __restrict__ ei, const float* __restrict__ ew,
                        const float* __restrict__ dinv, float* __restrict__ M){
  int i = blockIdx.x*256 + threadIdx.x;
  if (i >= NE_) return;
  int s = ei[i], d = ei[NE_ + i];
  float nrm = ew[i] * dinv[s] * dinv[d];
  int b = d / NV_;
  atomicAdd(&M[(b*NV_ + (d - b*NV_))*NV_ + (s - b*NV_)], nrm);
}

// ---------- fused projections: xz, x_dbl -> u, silu(z), dtr, B, C ----------
__global__ __launch_bounds__(256)
void k_proj(const float* __restrict__ xin, const float* __restrict__ inw,
            const float* __restrict__ xpw,
            bf16* __restrict__ u, bf16* __restrict__ zs,
            float* __restrict__ dtr, bf16* __restrict__ Bm, bf16* __restrict__ Cm){
  __shared__ float inT[32*129];   // [d][e], e<128, pad 129
  __shared__ float xpT[64*35];    // [e][j], j<34, pad 35
  __shared__ float xl[4][32];
  __shared__ float xh[4][64];
  int tid = threadIdx.x;
  for (int i = tid; i < 128*32; i += 256){
    int e = i >> 5, d = i & 31;
    inT[d*129 + e] = inw[i];
  }
  for (int i = tid; i < 34*64; i += 256){
    int j = i >> 6, e = i & 63;
    xpT[e*35 + j] = xpw[i];
  }
  int w = tid >> 6, lane = tid & 63;
  int r = blockIdx.x*4 + w;                 // r = node*256 + l
  if (lane < 32) xl[w][lane] = xin[r*32 + lane];
  __syncthreads();
  float a0 = 0.f, a1 = 0.f;
  #pragma unroll
  for (int d = 0; d < 32; d++){
    float xv = xl[w][d];
    a0 = fmaf(inT[d*129 + lane], xv, a0);
    a1 = fmaf(inT[d*129 + 64 + lane], xv, a1);
  }
  int node = r >> 8, l = r & 255;
  long ob = (long)l*NN_ + node;             // t-major layout
  u[ob*64 + lane] = f2b(a0);
  zs[ob*64 + lane] = f2b(a1 / (1.f + expf(-a1)));
  xh[w][lane] = a0;
  __syncthreads();
  if (lane < 34){
    float acc = 0.f;
    #pragma unroll
    for (int e = 0; e < 64; e++) acc = fmaf(xpT[e*35 + lane], xh[w][e], acc);
    if (lane < 2)       dtr[ob*2 + lane] = acc;
    else if (lane < 18) Bm[ob*16 + lane - 2] = f2b(acc);
    else                Cm[ob*16 + lane - 18] = f2b(acc);
  }
}

// ---------- uB = gcn_vec(u_t, gB) for all t (state-independent) ----------
__global__ __launch_bounds__(256)
void k_ub(const bf16* __restrict__ u, const float* __restrict__ gBw,
          const float* __restrict__ gBb, const float* __restrict__ Mg,
          bf16* __restrict__ uB){
  __shared__ float uL[19*64];
  __shared__ float wT[64*65];     // [d][e] pad 65
  __shared__ float hL[20*64];
  __shared__ float MLP[640];      // [vp][vg*8+k] = M_pad[vg+4k][vp]
  int t = blockIdx.x >> 5, b = blockIdx.x & 31;
  int tid = threadIdx.x;
  const bf16* up = u + ((long)t*NN_ + b*19)*64;
  for (int i = tid; i < 1216; i += 256) uL[i] = b2f(up[i]);
  for (int i = tid; i < 4096; i += 256){
    int e = i >> 6, d = i & 63;
    wT[d*65 + e] = gBw[i];
  }
  for (int i = tid; i < 640; i += 256){
    int vp = i >> 5, c = i & 31, g = c >> 3, k = c & 7;
    int v = g + 4*k;
    MLP[i] = (k < 5 && vp < 19 && v < 19) ? Mg[b*361 + v*19 + vp] : 0.f;
  }
  __syncthreads();
  int vg = tid >> 6, e = tid & 63;
  int v0 = vg, v1 = vg+4, v2 = vg+8, v3 = vg+12, v4 = vg+16;
  int v4c = (vg == 3) ? 18 : v4;            // clamped for loads
  float h0=0.f,h1=0.f,h2=0.f,h3=0.f,h4=0.f;
  #pragma unroll
  for (int d = 0; d < 64; d++){
    float wv = wT[d*65 + e];
    h0 = fmaf(wv, uL[v0*64 + d], h0);
    h1 = fmaf(wv, uL[v1*64 + d], h1);
    h2 = fmaf(wv, uL[v2*64 + d], h2);
    h3 = fmaf(wv, uL[v3*64 + d], h3);
    h4 = fmaf(wv, uL[v4c*64 + d], h4);
  }
  hL[v0*64 + e] = h0; hL[v1*64 + e] = h1; hL[v2*64 + e] = h2;
  hL[v3*64 + e] = h3; hL[v4*64 + e] = h4;
  __syncthreads();
  float bb = gBb[e];
  float acc0=bb, acc1=bb, acc2=bb, acc3=bb, acc4=bb;
  const float* mlb = MLP + vg*8;
  #pragma unroll
  for (int vp = 0; vp < 20; vp++){
    float hv = hL[vp*64 + e];
    float4 m4 = *(const float4*)(mlb + vp*32);
    float  m5 = mlb[vp*32 + 4];
    acc0 = fmaf(m4.x, hv, acc0); acc1 = fmaf(m4.y, hv, acc1);
    acc2 = fmaf(m4.z, hv, acc2); acc3 = fmaf(m4.w, hv, acc3);
    acc4 = fmaf(m5,  hv, acc4);
  }
  bf16* op = uB + ((long)t*NN_ + b*19)*64;
  op[v0*64 + e] = f2b(acc0);
  op[v1*64 + e] = f2b(acc1);
  op[v2*64 + e] = f2b(acc2);
  op[v3*64 + e] = f2b(acc3);
  if (vg != 3) op[v4*64 + e] = f2b(acc4);
}

// ---------- MFMA scan: block = (batch, n-pair); team (tid>>8) owns one n ----
// Transpose-free chain (16x16x32 bf16 MFMA, layouts per cdna4 guide):
//  S[32v][72pad] bf16 --Afrag--> D1[v][e] (B=Wa^T in VGPRs) --b64--> Hst[64e][40pad]
//  --Afrag--> D2[e][v] (B=M^T in VGPRs, acc init=bias) --update--> S
// v padded 19->32 (S pad rows stay 0 => Hst pad cols 0 => M garbage*0 = 0).
__global__ __launch_bounds__(512)
void k_scan(const float* __restrict__ Mg, const float* __restrict__ dtrg,
            const bf16* __restrict__ uBg, const bf16* __restrict__ Bg,
            const bf16* __restrict__ Cg,
            const float* __restrict__ gAw, const float* __restrict__ gAb,
            const float* __restrict__ gCw, const float* __restrict__ gCb,
            const float* __restrict__ Alog, const float* __restrict__ dtw,
            const float* __restrict__ dtb, bf16* __restrict__ yp)
{
  __shared__ short Sb[2*32*72];
  __shared__ short Hb[2*64*40];
  __shared__ float Yb[2*32*72];
  int b = blockIdx.x >> 3, npair = blockIdx.x & 7;
  int tid = threadIdx.x;
  int team = tid >> 8;                 // 0/1 -> n = 2*npair+team
  int w    = (tid >> 6) & 3;           // wave within team
  int lane = tid & 63;
  int l15  = lane & 15, quad = lane >> 4;
  int n = npair*2 + team;

  for (int i = tid; i < 2*32*72; i += 512) Sb[i] = 0;

  // ---- static fragments in VGPRs ----
  int mtp  = w >> 1;                   // phase m(v)-tile
  int ntp0 = 2*(w & 1);                // phase n(e)-tiles {ntp0, ntp0+1}
  // Wa^T / Wc^T B-frags: element j = W[(16nt+l15)][ks*32+quad*8+j]
  bf16x8 waf[1]; (void)waf;
  const float* wr;
  bf16x8 wa00, wa01, wa10, wa11, wc00, wc01, wc10, wc11;
  {
    float4 lo, hi;
    #define LDW(dst, Wp, nt, ks) \
      wr = Wp + (16*(nt) + l15)*64 + (ks)*32 + quad*8; \
      lo = *(const float4*)wr; hi = *(const float4*)(wr + 4); \
      dst[0]=(short)f2bs(lo.x); dst[1]=(short)f2bs(lo.y); \
      dst[2]=(short)f2bs(lo.z); dst[3]=(short)f2bs(lo.w); \
      dst[4]=(short)f2bs(hi.x); dst[5]=(short)f2bs(hi.y); \
      dst[6]=(short)f2bs(hi.z); dst[7]=(short)f2bs(hi.w);
    LDW(wa00, gAw, ntp0,   0) LDW(wa01, gAw, ntp0,   1)
    LDW(wa10, gAw, ntp0+1, 0) LDW(wa11, gAw, ntp0+1, 1)
    LDW(wc00, gCw, ntp0,   0) LDW(wc01, gCw, ntp0,   1)
    LDW(wc10, gCw, ntp0+1, 0) LDW(wc11, gCw, ntp0+1, 1)
    #undef LDW
  }
  // M^T B-frags for agg (n=v tiles 0,1): element j = M[vrow][quad*8+j]
  bf16x8 mf0, mf1;
  {
    const float* mb = Mg + b*361;
    int r0 = l15;  if (r0 > 18) r0 = 18;
    int r1 = (16 + l15 > 18) ? 18 : 16 + l15;
    #pragma unroll
    for (int j = 0; j < 8; j++){
      int vp = quad*8 + j;
      float m0 = (vp < 19) ? mb[r0*19 + vp] : 0.f;
      float m1 = (vp < 19) ? mb[r1*19 + vp] : 0.f;
      mf0[j] = (short)f2bs(m0);
      mf1[j] = (short)f2bs(m1);
    }
  }
  // per-lane e-params (agg e-tile = w): e0 = 16w + 4*quad
  int e0 = 16*w + 4*quad;
  float4 gab = *(const float4*)(gAb + e0);
  float4 gcb = *(const float4*)(gCb + e0);
  float4 db4 = *(const float4*)(dtb + e0);
  float4 dw0 = *(const float4*)(dtw + e0*2);      // w0(e0),w1(e0),w0(e0+1),w1(e0+1)
  float4 dw1 = *(const float4*)(dtw + e0*2 + 4);
  float w0r0=dw0.x, w1r0=dw0.y, w0r1=dw0.z, w1r1=dw0.w;
  float w0r2=dw1.x, w1r2=dw1.y, w0r3=dw1.z, w1r3=dw1.w;
  float An0 = -__expf(Alog[(e0+0)*16 + n]);
  float An1 = -__expf(Alog[(e0+1)*16 + n]);
  float An2 = -__expf(Alog[(e0+2)*16 + n]);
  float An3 = -__expf(Alog[(e0+3)*16 + n]);

  short* Sme = Sb + team*32*72;
  short* Hme = Hb + team*64*40;
  float* Yme = Yb + team*32*72;

  int va  = l15;                       // agg tile0 v (always < 19)
  int v1  = 16 + l15;                  // agg tile1 v
  int v1c = (v1 > 18) ? 18 : v1;
  bool v1ok = (v1 < 19);
  int nodeBase = b*19;
  // phase A-frag source rows / write coords
  int prow = (16*mtp + l15)*72;        // S row offset (shorts)
  int hrow0 = (16*ntp0 + l15)*40;      // Hst rows for the wave's two e-tiles
  int hrow1 = (16*(ntp0+1) + l15)*40;
  int v0h = 16*mtp + quad*4;           // Hst v-offset written by phase
  int arow = (16*w + l15)*40;          // Hst row read by agg (e-row)

  __syncthreads();

  for (int t = 0; t < 256; t++){
    long tb = (long)t*NN_ + nodeBase;
    // prefetch globals for the update/y (consumed after the MFMAs)
    float2 ra = *(const float2*)(dtrg + (tb + va)*2);
    float2 rb = *(const float2*)(dtrg + (tb + v1c)*2);
    uint2 uba = *(const uint2*)(uBg + (tb + va)*64 + e0);
    uint2 ubb = *(const uint2*)(uBg + (tb + v1c)*64 + e0);
    float Bva = b2f(Bg[(tb + va)*16 + n]),  Bvb = b2f(Bg[(tb + v1c)*16 + n]);
    float Cva = b2f(Cg[(tb + va)*16 + n]),  Cvb = b2f(Cg[(tb + v1c)*16 + n]);

    // ---- phase A: D1[v][e] = S . Wa^T ----
    {
      bf16x8 a0 = *(const bf16x8*)(Sme + prow + quad*8);
      bf16x8 a1 = *(const bf16x8*)(Sme + prow + 32 + quad*8);
      f32x4 p0 = {0.f,0.f,0.f,0.f}, p1 = {0.f,0.f,0.f,0.f};
      p0 = __builtin_amdgcn_mfma_f32_16x16x32_bf16(a0, wa00, p0, 0,0,0);
      p0 = __builtin_amdgcn_mfma_f32_16x16x32_bf16(a1, wa01, p0, 0,0,0);
      p1 = __builtin_amdgcn_mfma_f32_16x16x32_bf16(a0, wa10, p1, 0,0,0);
      p1 = __builtin_amdgcn_mfma_f32_16x16x32_bf16(a1, wa11, p1, 0,0,0);
      uint2 h0; h0.x = pk2(p0[0], p0[1]); h0.y = pk2(p0[2], p0[3]);
      uint2 h1; h1.x = pk2(p1[0], p1[1]); h1.y = pk2(p1[2], p1[3]);
      *(uint2*)(Hme + hrow0 + v0h) = h0;
      *(uint2*)(Hme + hrow1 + v0h) = h1;
    }
    __syncthreads();
    // ---- agg A: D2[e][v] = Hst . M^T (+gAb) ; then state update ----
    {
      bf16x8 hf = *(const bf16x8*)(Hme + arow + quad*8);
      f32x4 qa = {gab.x, gab.y, gab.z, gab.w};
      f32x4 qb = qa;
      qa = __builtin_amdgcn_mfma_f32_16x16x32_bf16(hf, mf0, qa, 0,0,0);
      qb = __builtin_amdgcn_mfma_f32_16x16x32_bf16(hf, mf1, qb, 0,0,0);
      // tile a (v = va, real always)
      float d0 = fmaf(ra.x, w0r0, fmaf(ra.y, w1r0, db4.x));
      float d1 = fmaf(ra.x, w0r1, fmaf(ra.y, w1r1, db4.y));
      float d2 = fmaf(ra.x, w0r2, fmaf(ra.y, w1r2, db4.z));
      float d3 = fmaf(ra.x, w0r3, fmaf(ra.y, w1r3, db4.w));
      float s0 = fsoftplus(d0), s1 = fsoftplus(d1);
      float s2 = fsoftplus(d2), s3 = fsoftplus(d3);
      float u0 = busf((unsigned short)(uba.x & 0xffff));
      float u1 = busf((unsigned short)(uba.x >> 16));
      float u2 = busf((unsigned short)(uba.y & 0xffff));
      float u3 = busf((unsigned short)(uba.y >> 16));
      float x0 = fmaf(qa[0], __expf(s0*An0), u0*s0*Bva);
      float x1 = fmaf(qa[1], __expf(s1*An1), u1*s1*Bva);
      float x2 = fmaf(qa[2], __expf(s2*An2), u2*s2*Bva);
      float x3 = fmaf(qa[3], __expf(s3*An3), u3*s3*Bva);
      uint2 sv; sv.x = pk2(x0, x1); sv.y = pk2(x2, x3);
      *(uint2*)(Sme + va*72 + e0) = sv;
      // tile b (v = v1, masked if pad)
      d0 = fmaf(rb.x, w0r0, fmaf(rb.y, w1r0, db4.x));
      d1 = fmaf(rb.x, w0r1, fmaf(rb.y, w1r1, db4.y));
      d2 = fmaf(rb.x, w0r2, fmaf(rb.y, w1r2, db4.z));
      d3 = fmaf(rb.x, w0r3, fmaf(rb.y, w1r3, db4.w));
      s0 = fsoftplus(d0); s1 = fsoftplus(d1);
      s2 = fsoftplus(d2); s3 = fsoftplus(d3);
      u0 = busf((unsigned short)(ubb.x & 0xffff));
      u1 = busf((unsigned short)(ubb.x >> 16));
      u2 = busf((unsigned short)(ubb.y & 0xffff));
      u3 = busf((unsigned short)(ubb.y >> 16));
      x0 = fmaf(qb[0], __expf(s0*An0), u0*s0*Bvb);
      x1 = fmaf(qb[1], __expf(s1*An1), u1*s1*Bvb);
      x2 = fmaf(qb[2], __expf(s2*An2), u2*s2*Bvb);
      x3 = fmaf(qb[3], __expf(s3*An3), u3*s3*Bvb);
      if (!v1ok){ x0 = 0.f; x1 = 0.f; x2 = 0.f; x3 = 0.f; }
      uint2 sw2; sw2.x = pk2(x0, x1); sw2.y = pk2(x2, x3);
      *(uint2*)(Sme + v1*72 + e0) = sw2;
    }
    __syncthreads();
    // ---- phase C: D3[v][e] = S . Wc^T ----
    {
      bf16x8 a0 = *(const bf16x8*)(Sme + prow + quad*8);
      bf16x8 a1 = *(const bf16x8*)(Sme + prow + 32 + quad*8);
      f32x4 p0 = {0.f,0.f,0.f,0.f}, p1 = {0.f,0.f,0.f,0.f};
      p0 = __builtin_amdgcn_mfma_f32_16x16x32_bf16(a0, wc00, p0, 0,0,0);
      p0 = __builtin_amdgcn_mfma_f32_16x16x32_bf16(a1, wc01, p0, 0,0,0);
      p1 = __builtin_amdgcn_mfma_f32_16x16x32_bf16(a0, wc10, p1, 0,0,0);
      p1 = __builtin_amdgcn_mfma_f32_16x16x32_bf16(a1, wc11, p1, 0,0,0);
      uint2 h0; h0.x = pk2(p0[0], p0[1]); h0.y = pk2(p0[2], p0[3]);
      uint2 h1; h1.x = pk2(p1[0], p1[1]); h1.y = pk2(p1[2], p1[3]);
      *(uint2*)(Hme + hrow0 + v0h) = h0;
      *(uint2*)(Hme + hrow1 + v0h) = h1;
    }
    __syncthreads();
    // ---- agg C: D4[e][v] = Hst . M^T (+gCb); y = sC*C -> Yb ----
    {
      bf16x8 hf = *(const bf16x8*)(Hme + arow + quad*8);
      f32x4 qa = {gcb.x, gcb.y, gcb.z, gcb.w};
      f32x4 qb = qa;
      qa = __builtin_amdgcn_mfma_f32_16x16x32_bf16(hf, mf0, qa, 0,0,0);
      qb = __builtin_amdgcn_mfma_f32_16x16x32_bf16(hf, mf1, qb, 0,0,0);
      float4 ya; ya.x = qa[0]*Cva; ya.y = qa[1]*Cva; ya.z = qa[2]*Cva; ya.w = qa[3]*Cva;
      float4 yb; yb.x = qb[0]*Cvb; yb.y = qb[1]*Cvb; yb.z = qb[2]*Cvb; yb.w = qb[3]*Cvb;
      *(float4*)(Yme + va*72 + e0) = ya;
      *(float4*)(Yme + v1*72 + e0) = yb;
    }
    __syncthreads();
    // ---- team0 sums both n's and stores the pair-partial ----
    if (team == 0){
      float4 sa = *(const float4*)(Yb + va*72 + e0);
      float4 sb4 = *(const float4*)(Yb + 32*72 + va*72 + e0);
      uint2 ov;
      ov.x = pk2(sa.x + sb4.x, sa.y + sb4.y);
      ov.y = pk2(sa.z + sb4.z, sa.w + sb4.w);
      *(uint2*)(yp + (((long)npair*256 + t)*NN_ + nodeBase + va)*64 + e0) = ov;
      if (v1ok){
        float4 ta = *(const float4*)(Yb + v1*72 + e0);
        float4 tb4 = *(const float4*)(Yb + 32*72 + v1*72 + e0);
        uint2 o2;
        o2.x = pk2(ta.x + tb4.x, ta.y + tb4.y);
        o2.y = pk2(ta.z + tb4.z, ta.w + tb4.w);
        *(uint2*)(yp + (((long)npair*256 + t)*NN_ + nodeBase + v1)*64 + e0) = o2;
      }
    }
  }
}

// ---------- reduce partials, gate, out_proj ----------
__global__ __launch_bounds__(256)
void k_final(const bf16* __restrict__ yp, const bf16* __restrict__ u,
             const bf16* __restrict__ zs, const float* __restrict__ Dp,
             const float* __restrict__ ow, float* __restrict__ out)
{
  __shared__ float oT[64*33];   // [e][o] pad 33
  __shared__ float yl[4][64];
  int tid = threadIdx.x;
  for (int i = tid; i < 32*64; i += 256){
    int o = i >> 6, e = i & 63;
    oT[e*33 + o] = ow[i];
  }
  int w = tid >> 6, lane = tid & 63;
  long r = (long)blockIdx.x*4 + w;        // r = t*608 + node
  long base = r*64;
  float y = Dp[lane] * b2f(u[base + lane]);
  #pragma unroll
  for (int p = 0; p < 8; p++) y += b2f(yp[(long)p*NTOT + base + lane]);
  y *= b2f(zs[base + lane]);
  yl[w][lane] = y;
  __syncthreads();
  if (lane < 32){
    float acc = 0.f;
    #pragma unroll
    for (int e = 0; e < 64; e++) acc = fmaf(oT[e*33 + lane], yl[w][e], acc);
    int t = (int)(r / NN_), node = (int)(r - (long)t*NN_);
    out[((long)node*256 + t)*32 + lane] = acc;
  }
}

extern "C" void kernel_launch(void* const* d_in, const int* in_sizes, int n_in,
                              void* d_out, int out_size, void* d_ws, size_t ws_size,
                              hipStream_t stream)
{
  (void)in_sizes; (void)n_in; (void)out_size; (void)ws_size;
  const float* xin = (const float*)d_in[0];
  const int*   ei  = (const int*)  d_in[1];
  const float* ew  = (const float*)d_in[2];
  const float* inw = (const float*)d_in[3];
  const float* xpw = (const float*)d_in[4];
  const float* dtw = (const float*)d_in[5];
  const float* dtb = (const float*)d_in[6];
  const float* Alog= (const float*)d_in[7];
  const float* Dp  = (const float*)d_in[8];
  const float* ow  = (const float*)d_in[9];
  const float* gAw = (const float*)d_in[10];
  const float* gAb = (const float*)d_in[11];
  const float* gBw = (const float*)d_in[12];
  const float* gBb = (const float*)d_in[13];
  const float* gCw = (const float*)d_in[14];
  const float* gCb = (const float*)d_in[15];
  float* out = (float*)d_out;

  float* Mg   = (float*)d_ws;            // 11552 f32
  float* deg  = Mg + 11552;              // 608
  float* dinv = deg + 608;               // 608
  float* dtr  = dinv + 608;              // 2*NROWS f32
  bf16*  u    = (bf16*)(dtr + 2*NROWS);  // NTOT bf16
  bf16*  zs   = u + NTOT;
  bf16*  uB   = zs + NTOT;
  bf16*  Bm   = uB + NTOT;               // NBC
  bf16*  Cm   = Bm + NBC;                // NBC
  bf16*  yp   = Cm + NBC;                // 8*NTOT   (total ws ~230 MB)

  hipMemsetAsync(d_ws, 0, (11552 + 608)*sizeof(float), stream);  // M + deg
  k_deg  <<<(NE_ + 255)/256, 256, 0, stream>>>(ei, ew, deg);
  k_dinv <<<(NN_ + 255)/256, 256, 0, stream>>>(deg, dinv, Mg);
  k_edges<<<(NE_ + 255)/256, 256, 0, stream>>>(ei, ew, dinv, Mg);
  k_proj <<<NROWS/4, 256, 0, stream>>>(xin, inw, xpw, u, zs, dtr, Bm, Cm);
  k_ub   <<<LL_*NB_, 256, 0, stream>>>(u, gBw, gBb, Mg, uB);
  k_scan <<<NB_*8, 512, 0, stream>>>(Mg, dtr, uB, Bm, Cm, gAw, gAb, gCw, gCb,
                                     Alog, dtw, dtb, yp);
  k_final<<<NROWS/4, 256, 0, stream>>>(yp, u, zs, Dp, ow, out);
}

// Round 8
// 992.654 us; speedup vs baseline: 22.1891x; 1.0028x over previous
//
#include <hip/hip_runtime.h>
#include <hip/hip_bf16.h>

typedef __hip_bfloat16 bf16;
typedef __attribute__((ext_vector_type(8))) short bf16x8;
typedef __attribute__((ext_vector_type(4))) float f32x4;

#define NV_   19
#define NB_   32
#define NN_   608
#define LL_   256
#define NE_   10944
#define NROWS (NN_*LL_)      // 155648
#define NTOT  (NROWS*64)     // 9961472
#define NBC   (NROWS*16)     // 2490368

__device__ __forceinline__ float b2f(bf16 x){ return __bfloat162float(x); }
__device__ __forceinline__ bf16 f2b(float x){ return __float2bfloat16(x); }
__device__ __forceinline__ unsigned short f2bs(float x){
  union { float f; unsigned u; } c; c.f = x;
  unsigned r = c.u + 0x7FFFu + ((c.u >> 16) & 1u);
  return (unsigned short)(r >> 16);
}
__device__ __forceinline__ float busf(unsigned short s){
  union { unsigned u; float f; } c; c.u = ((unsigned)s) << 16; return c.f;
}
__device__ __forceinline__ unsigned pk2(float a, float b){
  return (unsigned)f2bs(a) | ((unsigned)f2bs(b) << 16);
}
__device__ __forceinline__ float fsoftplus(float x){
  return fmaxf(x, 0.f) + __logf(1.f + __expf(-fabsf(x)));
}

// ---------- GCN norm precompute ----------
__global__ void k_deg(const int* __restrict__ ei, const float* __restrict__ ew,
                      float* __restrict__ deg){
  int i = blockIdx.x*256 + threadIdx.x;
  if (i < NN_) atomicAdd(&deg[i], 1.0f);              // self loop weight 1
  if (i < NE_) atomicAdd(&deg[ei[NE_ + i]], ew[i]);
}

__global__ void k_dinv(const float* __restrict__ deg, float* __restrict__ dinv,
                       float* __restrict__ M){
  int v = blockIdx.x*256 + threadIdx.x;
  if (v >= NN_) return;
  float r = rsqrtf(fmaxf(deg[v], 1e-12f));
  dinv[v] = r;
  int b = v / NV_, lv = v - b*NV_;
  M[(b*NV_ + lv)*NV_ + lv] = r*r;                     // self-loop norm
}

__global__ void k_edges(const int* __restrict__ ei, const float* __restrict__ ew,
                        const float* __restrict__ dinv, float* __restrict__ M){
  int i = blockIdx.x*256 + threadIdx.x;
  if (i >= NE_) return;
  int s = ei[i], d = ei[NE_ + i];
  float nrm = ew[i] * dinv[s] * dinv[d];
  int b = d / NV_;
  atomicAdd(&M[(b*NV_ + (d - b*NV_))*NV_ + (s - b*NV_)], nrm);
}

// ---------- fused projections: xz, x_dbl -> u, silu(z), dtr, B, C ----------
__global__ __launch_bounds__(256)
void k_proj(const float* __restrict__ xin, const float* __restrict__ inw,
            const float* __restrict__ xpw,
            bf16* __restrict__ u, bf16* __restrict__ zs,
            float* __restrict__ dtr, bf16* __restrict__ Bm, bf16* __restrict__ Cm){
  __shared__ float inT[32*129];   // [d][e], e<128, pad 129
  __shared__ float xpT[64*35];    // [e][j], j<34, pad 35
  __shared__ float xl[4][32];
  __shared__ float xh[4][64];
  int tid = threadIdx.x;
  for (int i = tid; i < 128*32; i += 256){
    int e = i >> 5, d = i & 31;
    inT[d*129 + e] = inw[i];
  }
  for (int i = tid; i < 34*64; i += 256){
    int j = i >> 6, e = i & 63;
    xpT[e*35 + j] = xpw[i];
  }
  int w = tid >> 6, lane = tid & 63;
  int r = blockIdx.x*4 + w;                 // r = node*256 + l
  if (lane < 32) xl[w][lane] = xin[r*32 + lane];
  __syncthreads();
  float a0 = 0.f, a1 = 0.f;
  #pragma unroll
  for (int d = 0; d < 32; d++){
    float xv = xl[w][d];
    a0 = fmaf(inT[d*129 + lane], xv, a0);
    a1 = fmaf(inT[d*129 + 64 + lane], xv, a1);
  }
  int node = r >> 8, l = r & 255;
  long ob = (long)l*NN_ + node;             // t-major layout
  u[ob*64 + lane] = f2b(a0);
  zs[ob*64 + lane] = f2b(a1 / (1.f + expf(-a1)));
  xh[w][lane] = a0;
  __syncthreads();
  if (lane < 34){
    float acc = 0.f;
    #pragma unroll
    for (int e = 0; e < 64; e++) acc = fmaf(xpT[e*35 + lane], xh[w][e], acc);
    if (lane < 2)       dtr[ob*2 + lane] = acc;
    else if (lane < 18) Bm[ob*16 + lane - 2] = f2b(acc);
    else                Cm[ob*16 + lane - 18] = f2b(acc);
  }
}

// ---------- uB = gcn_vec(u_t, gB) for all t (state-independent) ----------
__global__ __launch_bounds__(256)
void k_ub(const bf16* __restrict__ u, const float* __restrict__ gBw,
          const float* __restrict__ gBb, const float* __restrict__ Mg,
          bf16* __restrict__ uB){
  __shared__ float uL[19*64];
  __shared__ float wT[64*65];     // [d][e] pad 65
  __shared__ float hL[20*64];
  __shared__ float MLP[640];      // [vp][vg*8+k] = M_pad[vg+4k][vp]
  int t = blockIdx.x >> 5, b = blockIdx.x & 31;
  int tid = threadIdx.x;
  const bf16* up = u + ((long)t*NN_ + b*19)*64;
  for (int i = tid; i < 1216; i += 256) uL[i] = b2f(up[i]);
  for (int i = tid; i < 4096; i += 256){
    int e = i >> 6, d = i & 63;
    wT[d*65 + e] = gBw[i];
  }
  for (int i = tid; i < 640; i += 256){
    int vp = i >> 5, c = i & 31, g = c >> 3, k = c & 7;
    int v = g + 4*k;
    MLP[i] = (k < 5 && vp < 19 && v < 19) ? Mg[b*361 + v*19 + vp] : 0.f;
  }
  __syncthreads();
  int vg = tid >> 6, e = tid & 63;
  int v0 = vg, v1 = vg+4, v2 = vg+8, v3 = vg+12, v4 = vg+16;
  int v4c = (vg == 3) ? 18 : v4;            // clamped for loads
  float h0=0.f,h1=0.f,h2=0.f,h3=0.f,h4=0.f;
  #pragma unroll
  for (int d = 0; d < 64; d++){
    float wv = wT[d*65 + e];
    h0 = fmaf(wv, uL[v0*64 + d], h0);
    h1 = fmaf(wv, uL[v1*64 + d], h1);
    h2 = fmaf(wv, uL[v2*64 + d], h2);
    h3 = fmaf(wv, uL[v3*64 + d], h3);
    h4 = fmaf(wv, uL[v4c*64 + d], h4);
  }
  hL[v0*64 + e] = h0; hL[v1*64 + e] = h1; hL[v2*64 + e] = h2;
  hL[v3*64 + e] = h3; hL[v4*64 + e] = h4;
  __syncthreads();
  float bb = gBb[e];
  float acc0=bb, acc1=bb, acc2=bb, acc3=bb, acc4=bb;
  const float* mlb = MLP + vg*8;
  #pragma unroll
  for (int vp = 0; vp < 20; vp++){
    float hv = hL[vp*64 + e];
    float4 m4 = *(const float4*)(mlb + vp*32);
    float  m5 = mlb[vp*32 + 4];
    acc0 = fmaf(m4.x, hv, acc0); acc1 = fmaf(m4.y, hv, acc1);
    acc2 = fmaf(m4.z, hv, acc2); acc3 = fmaf(m4.w, hv, acc3);
    acc4 = fmaf(m5,  hv, acc4);
  }
  bf16* op = uB + ((long)t*NN_ + b*19)*64;
  op[v0*64 + e] = f2b(acc0);
  op[v1*64 + e] = f2b(acc1);
  op[v2*64 + e] = f2b(acc2);
  op[v3*64 + e] = f2b(acc3);
  if (vg != 3) op[v4*64 + e] = f2b(acc4);
}

// ---------- MFMA scan v2: 1024-thr block = (batch, n-pair); 2 teams x 8 waves ----
// R7 post-mortem: 2 waves/SIMD couldn't hide the 4-phase LDS->MFMA->pack chains
// (VALUBusy 48%, step 6070cyc). v2: 16 waves/CU (4/SIMD), each wave owns ONE
// MFMA tile per phase; Hst double-buffered (3 barriers/step, not 4); team-pair
// y-sum deferred one step through a bf16 exchange buffer so yp stays 8 slices
// (ws unchanged; suspected ws cap ~256MB).
__global__ __launch_bounds__(1024)
void k_scan(const float* __restrict__ Mg, const float* __restrict__ dtrg,
            const bf16* __restrict__ uBg, const bf16* __restrict__ Bg,
            const bf16* __restrict__ Cg,
            const float* __restrict__ gAw, const float* __restrict__ gAb,
            const float* __restrict__ gCw, const float* __restrict__ gCb,
            const float* __restrict__ Alog, const float* __restrict__ dtw,
            const float* __restrict__ dtb, bf16* __restrict__ yp)
{
  __shared__ __align__(16) short Sb[2*32*72];
  __shared__ __align__(16) short H0[2*64*40];
  __shared__ __align__(16) short H1[2*64*40];
  __shared__ __align__(16) short Yx[32*64];
  int b = blockIdx.x >> 3, npair = blockIdx.x & 7;
  int tid = threadIdx.x;
  int team = tid >> 9;                  // 0/1 -> n = 2*npair+team
  int tw   = (tid >> 6) & 7;            // wave within team
  int lane = tid & 63;
  int l15  = lane & 15, quad = lane >> 4;
  int n = npair*2 + team;
  // wave roles
  int mt = tw >> 2;                     // phase m(v)-tile
  int nt = tw & 3;                      // phase n(e)-tile
  int et = tw >> 1;                     // agg e-tile
  int vt = tw & 1;                      // agg v-tile

  for (int i = tid; i < 2*32*72; i += 1024) Sb[i] = 0;

  // phase B-frags (Wa^T/Wc^T): element j = W[16nt+l15][kc*32 + quad*8 + j]
  bf16x8 wa0, wa1, wc0, wc1;
  {
    #define PACK8(dst, p) { float4 lo_ = *(const float4*)(p); \
      float4 hi_ = *(const float4*)((p)+4); \
      dst[0]=(short)f2bs(lo_.x); dst[1]=(short)f2bs(lo_.y); \
      dst[2]=(short)f2bs(lo_.z); dst[3]=(short)f2bs(lo_.w); \
      dst[4]=(short)f2bs(hi_.x); dst[5]=(short)f2bs(hi_.y); \
      dst[6]=(short)f2bs(hi_.z); dst[7]=(short)f2bs(hi_.w); }
    const float* wrA = gAw + (16*nt + l15)*64 + quad*8;
    const float* wrC = gCw + (16*nt + l15)*64 + quad*8;
    PACK8(wa0, wrA) PACK8(wa1, wrA + 32)
    PACK8(wc0, wrC) PACK8(wc1, wrC + 32)
    #undef PACK8
  }
  // agg B-frag (M^T): element j = M[16vt+l15][quad*8+j], zero-padded
  bf16x8 mf;
  {
    const float* mb = Mg + b*361;
    int vr = 16*vt + l15; if (vr > 18) vr = 18;
    #pragma unroll
    for (int j = 0; j < 8; j++){
      int vp = quad*8 + j;
      mf[j] = (short)f2bs((vp < 19) ? mb[vr*19 + vp] : 0.f);
    }
  }
  // agg-lane constants: e0 = 16et + 4quad, v = 16vt + l15
  int e0 = 16*et + 4*quad;
  int v_ = 16*vt + l15;
  int vc = (v_ > 18) ? 18 : v_;
  bool vok = (v_ < 19);
  float4 gab = *(const float4*)(gAb + e0);
  float4 gcb = *(const float4*)(gCb + e0);
  float4 db4 = *(const float4*)(dtb + e0);
  float4 dw0 = *(const float4*)(dtw + e0*2);
  float4 dw1 = *(const float4*)(dtw + e0*2 + 4);
  float w0r0=dw0.x, w1r0=dw0.y, w0r1=dw0.z, w1r1=dw0.w;
  float w0r2=dw1.x, w1r2=dw1.y, w0r3=dw1.z, w1r3=dw1.w;
  float An0 = -__expf(Alog[(e0+0)*16 + n]);
  float An1 = -__expf(Alog[(e0+1)*16 + n]);
  float An2 = -__expf(Alog[(e0+2)*16 + n]);
  float An3 = -__expf(Alog[(e0+3)*16 + n]);

  short* Sme  = Sb + team*32*72;
  short* H0me = H0 + team*64*40;
  short* H1me = H1 + team*64*40;
  int nodeBase = b*19;
  const short* prS  = Sme + (16*mt + l15)*72 + quad*8;   // phase A-frag src
  short*       pwH0 = H0me + (16*nt + l15)*40 + 16*mt + quad*4;
  short*       pwH1 = H1me + (16*nt + l15)*40 + 16*mt + quad*4;
  const short* arH0 = H0me + (16*et + l15)*40 + quad*8;  // agg A-frag src
  const short* arH1 = H1me + (16*et + l15)*40 + quad*8;

  float py0=0.f, py1=0.f, py2=0.f, py3=0.f;   // deferred y (team 0)

  __syncthreads();

  for (int t = 0; t < 256; t++){
    long tb = (long)t*NN_ + nodeBase;
    // prefetch this step's update inputs (1 v-row per lane)
    float2 ra = *(const float2*)(dtrg + (tb + vc)*2);
    uint2 ub2 = *(const uint2*)(uBg + (tb + vc)*64 + e0);
    float Bv  = b2f(Bg[(tb + vc)*16 + n]);
    float Cv  = b2f(Cg[(tb + vc)*16 + n]);

    // ---- phase A: H0[e][v] = (S . Wa^T)^T ----
    {
      bf16x8 a0 = *(const bf16x8*)(prS);
      bf16x8 a1 = *(const bf16x8*)(prS + 32);
      f32x4 p = {0.f,0.f,0.f,0.f};
      p = __builtin_amdgcn_mfma_f32_16x16x32_bf16(a0, wa0, p, 0,0,0);
      p = __builtin_amdgcn_mfma_f32_16x16x32_bf16(a1, wa1, p, 0,0,0);
      uint2 h; h.x = pk2(p[0], p[1]); h.y = pk2(p[2], p[3]);
      *(uint2*)pwH0 = h;
    }
    __syncthreads();                                   // B1
    // ---- deferred pair-sum + store for t-1 (team 0 only) ----
    if (team == 0 && t > 0 && vok){
      uint2 yv = *(const uint2*)(Yx + v_*64 + e0);
      uint2 ov;
      ov.x = pk2(py0 + busf((unsigned short)(yv.x & 0xffff)),
                 py1 + busf((unsigned short)(yv.x >> 16)));
      ov.y = pk2(py2 + busf((unsigned short)(yv.y & 0xffff)),
                 py3 + busf((unsigned short)(yv.y >> 16)));
      *(uint2*)(yp + (((long)npair*256 + (t-1))*NN_ + nodeBase + v_)*64 + e0) = ov;
    }
    // ---- agg A: D[e][v] = H0 . M^T (+gAb); state update ----
    {
      bf16x8 hf = *(const bf16x8*)arH0;
      f32x4 q = {gab.x, gab.y, gab.z, gab.w};
      q = __builtin_amdgcn_mfma_f32_16x16x32_bf16(hf, mf, q, 0,0,0);
      float d0 = fmaf(ra.x, w0r0, fmaf(ra.y, w1r0, db4.x));
      float d1 = fmaf(ra.x, w0r1, fmaf(ra.y, w1r1, db4.y));
      float d2 = fmaf(ra.x, w0r2, fmaf(ra.y, w1r2, db4.z));
      float d3 = fmaf(ra.x, w0r3, fmaf(ra.y, w1r3, db4.w));
      float s0 = fsoftplus(d0), s1 = fsoftplus(d1);
      float s2 = fsoftplus(d2), s3 = fsoftplus(d3);
      float u0 = busf((unsigned short)(ub2.x & 0xffff));
      float u1 = busf((unsigned short)(ub2.x >> 16));
      float u2 = busf((unsigned short)(ub2.y & 0xffff));
      float u3 = busf((unsigned short)(ub2.y >> 16));
      float x0 = fmaf(q[0], __expf(s0*An0), u0*s0*Bv);
      float x1 = fmaf(q[1], __expf(s1*An1), u1*s1*Bv);
      float x2 = fmaf(q[2], __expf(s2*An2), u2*s2*Bv);
      float x3 = fmaf(q[3], __expf(s3*An3), u3*s3*Bv);
      if (!vok){ x0 = 0.f; x1 = 0.f; x2 = 0.f; x3 = 0.f; }
      uint2 sv; sv.x = pk2(x0, x1); sv.y = pk2(x2, x3);
      *(uint2*)(Sme + v_*72 + e0) = sv;
    }
    __syncthreads();                                   // B2
    // ---- phase C: H1[e][v] = (S . Wc^T)^T ----
    {
      bf16x8 a0 = *(const bf16x8*)(prS);
      bf16x8 a1 = *(const bf16x8*)(prS + 32);
      f32x4 p = {0.f,0.f,0.f,0.f};
      p = __builtin_amdgcn_mfma_f32_16x16x32_bf16(a0, wc0, p, 0,0,0);
      p = __builtin_amdgcn_mfma_f32_16x16x32_bf16(a1, wc1, p, 0,0,0);
      uint2 h; h.x = pk2(p[0], p[1]); h.y = pk2(p[2], p[3]);
      *(uint2*)pwH1 = h;
    }
    __syncthreads();                                   // B3
    // ---- agg C: D[e][v] = H1 . M^T (+gCb); y = D*Cv ----
    {
      bf16x8 hf = *(const bf16x8*)arH1;
      f32x4 q = {gcb.x, gcb.y, gcb.z, gcb.w};
      q = __builtin_amdgcn_mfma_f32_16x16x32_bf16(hf, mf, q, 0,0,0);
      float y0 = q[0]*Cv, y1 = q[1]*Cv, y2 = q[2]*Cv, y3 = q[3]*Cv;
      if (team == 1){
        uint2 yv; yv.x = pk2(y0, y1); yv.y = pk2(y2, y3);
        *(uint2*)(Yx + v_*64 + e0) = yv;
      } else {
        py0 = y0; py1 = y1; py2 = y2; py3 = y3;
      }
    }
    // no barrier: next phase A touches S (fenced by B2) and H0 (fenced by B1/B3)
  }
  __syncthreads();
  if (team == 0 && vok){
    uint2 yv = *(const uint2*)(Yx + v_*64 + e0);
    uint2 ov;
    ov.x = pk2(py0 + busf((unsigned short)(yv.x & 0xffff)),
               py1 + busf((unsigned short)(yv.x >> 16)));
    ov.y = pk2(py2 + busf((unsigned short)(yv.y & 0xffff)),
               py3 + busf((unsigned short)(yv.y >> 16)));
    *(uint2*)(yp + (((long)npair*256 + 255)*NN_ + nodeBase + v_)*64 + e0) = ov;
  }
}

// ---------- reduce partials, gate, out_proj ----------
__global__ __launch_bounds__(256)
void k_final(const bf16* __restrict__ yp, const bf16* __restrict__ u,
             const bf16* __restrict__ zs, const float* __restrict__ Dp,
             const float* __restrict__ ow, float* __restrict__ out)
{
  __shared__ float oT[64*33];   // [e][o] pad 33
  __shared__ float yl[4][64];
  int tid = threadIdx.x;
  for (int i = tid; i < 32*64; i += 256){
    int o = i >> 6, e = i & 63;
    oT[e*33 + o] = ow[i];
  }
  int w = tid >> 6, lane = tid & 63;
  long r = (long)blockIdx.x*4 + w;        // r = t*608 + node
  long base = r*64;
  float y = Dp[lane] * b2f(u[base + lane]);
  #pragma unroll
  for (int p = 0; p < 8; p++) y += b2f(yp[(long)p*NTOT + base + lane]);
  y *= b2f(zs[base + lane]);
  yl[w][lane] = y;
  __syncthreads();
  if (lane < 32){
    float acc = 0.f;
    #pragma unroll
    for (int e = 0; e < 64; e++) acc = fmaf(oT[e*33 + lane], yl[w][e], acc);
    int t = (int)(r / NN_), node = (int)(r - (long)t*NN_);
    out[((long)node*256 + t)*32 + lane] = acc;
  }
}

extern "C" void kernel_launch(void* const* d_in, const int* in_sizes, int n_in,
                              void* d_out, int out_size, void* d_ws, size_t ws_size,
                              hipStream_t stream)
{
  (void)in_sizes; (void)n_in; (void)out_size; (void)ws_size;
  const float* xin = (const float*)d_in[0];
  const int*   ei  = (const int*)  d_in[1];
  const float* ew  = (const float*)d_in[2];
  const float* inw = (const float*)d_in[3];
  const float* xpw = (const float*)d_in[4];
  const float* dtw = (const float*)d_in[5];
  const float* dtb = (const float*)d_in[6];
  const float* Alog= (const float*)d_in[7];
  const float* Dp  = (const float*)d_in[8];
  const float* ow  = (const float*)d_in[9];
  const float* gAw = (const float*)d_in[10];
  const float* gAb = (const float*)d_in[11];
  const float* gBw = (const float*)d_in[12];
  const float* gBb = (const float*)d_in[13];
  const float* gCw = (const float*)d_in[14];
  const float* gCb = (const float*)d_in[15];
  float* out = (float*)d_out;

  float* Mg   = (float*)d_ws;            // 11552 f32
  float* deg  = Mg + 11552;              // 608
  float* dinv = deg + 608;               // 608
  float* dtr  = dinv + 608;              // 2*NROWS f32
  bf16*  u    = (bf16*)(dtr + 2*NROWS);  // NTOT bf16
  bf16*  zs   = u + NTOT;
  bf16*  uB   = zs + NTOT;
  bf16*  Bm   = uB + NTOT;               // NBC
  bf16*  Cm   = Bm + NBC;                // NBC
  bf16*  yp   = Cm + NBC;                // 8*NTOT   (total ws ~230 MB)

  hipMemsetAsync(d_ws, 0, (11552 + 608)*sizeof(float), stream);  // M + deg
  k_deg  <<<(NE_ + 255)/256, 256, 0, stream>>>(ei, ew, deg);
  k_dinv <<<(NN_ + 255)/256, 256, 0, stream>>>(deg, dinv, Mg);
  k_edges<<<(NE_ + 255)/256, 256, 0, stream>>>(ei, ew, dinv, Mg);
  k_proj <<<NROWS/4, 256, 0, stream>>>(xin, inw, xpw, u, zs, dtr, Bm, Cm);
  k_ub   <<<LL_*NB_, 256, 0, stream>>>(u, gBw, gBb, Mg, uB);
  k_scan <<<NB_*8, 1024, 0, stream>>>(Mg, dtr, uB, Bm, Cm, gAw, gAb, gCw, gCb,
                                      Alog, dtw, dtb, yp);
  k_final<<<NROWS/4, 256, 0, stream>>>(yp, u, zs, Dp, ow, out);
}

// Round 9
// 699.527 us; speedup vs baseline: 31.4871x; 1.4190x over previous
//
#include <hip/hip_runtime.h>
#include <hip/hip_bf16.h>

typedef __hip_bfloat16 bf16;
typedef unsigned short ushort_t;
typedef __attribute__((ext_vector_type(8))) short bf16x8;
typedef __attribute__((ext_vector_type(4))) float f32x4;

#define NV_   19
#define NB_   32
#define NN_   608
#define LL_   256
#define NE_   10944
#define NROWS (NN_*LL_)      // 155648
#define NTOT  (NROWS*64)     // 9961472
#define NBC   (NROWS*16)     // 2490368

__device__ __forceinline__ float b2f(bf16 x){ return __bfloat162float(x); }
__device__ __forceinline__ bf16 f2b(float x){ return __float2bfloat16(x); }
__device__ __forceinline__ unsigned short f2bs(float x){
  union { float f; unsigned u; } c; c.f = x;
  unsigned r = c.u + 0x7FFFu + ((c.u >> 16) & 1u);
  return (unsigned short)(r >> 16);
}
__device__ __forceinline__ float busf(unsigned short s){
  union { unsigned u; float f; } c; c.u = ((unsigned)s) << 16; return c.f;
}
// packed f32x2 -> bf16x2 (RN) — lowers to v_cvt_pk_bf16_f32 where available
__device__ __forceinline__ unsigned pkrn(float a, float b){
  union { __hip_bfloat162 h2; unsigned u; } c;
  float2 t; t.x = a; t.y = b;
  c.h2 = __float22bfloat162_rn(t);
  return c.u;
}
__device__ __forceinline__ float blo(unsigned u){
  union { unsigned x; float f; } c; c.x = u << 16; return c.f;
}
__device__ __forceinline__ float bhi(unsigned u){
  union { unsigned x; float f; } c; c.x = u & 0xffff0000u; return c.f;
}
__device__ __forceinline__ float softplusf(float x){
  return fmaxf(x, 0.f) + log1pf(expf(-fabsf(x)));
}

// ---------- GCN norm precompute ----------
__global__ void k_deg(const int* __restrict__ ei, const float* __restrict__ ew,
                      float* __restrict__ deg){
  int i = blockIdx.x*256 + threadIdx.x;
  if (i < NN_) atomicAdd(&deg[i], 1.0f);              // self loop weight 1
  if (i < NE_) atomicAdd(&deg[ei[NE_ + i]], ew[i]);
}

__global__ void k_dinv(const float* __restrict__ deg, float* __restrict__ dinv,
                       float* __restrict__ M){
  int v = blockIdx.x*256 + threadIdx.x;
  if (v >= NN_) return;
  float r = rsqrtf(fmaxf(deg[v], 1e-12f));
  dinv[v] = r;
  int b = v / NV_, lv = v - b*NV_;
  M[(b*NV_ + lv)*NV_ + lv] = r*r;                     // self-loop norm
}

__global__ void k_edges(const int* __restrict__ ei, const float* __restrict__ ew,
                        const float* __restrict__ dinv, float* __restrict__ M){
  int i = blockIdx.x*256 + threadIdx.x;
  if (i >= NE_) return;
  int s = ei[i], d = ei[NE_ + i];
  float nrm = ew[i] * dinv[s] * dinv[d];
  int b = d / NV_;
  atomicAdd(&M[(b*NV_ + (d - b*NV_))*NV_ + (s - b*NV_)], nrm);
}

// ---------- fused projections (32 row-groups/block: weights loaded once) ----------
__global__ __launch_bounds__(256)
void k_proj(const float* __restrict__ xin, const float* __restrict__ inw,
            const float* __restrict__ xpw,
            bf16* __restrict__ u, bf16* __restrict__ zs,
            float* __restrict__ dtr, bf16* __restrict__ Bm, bf16* __restrict__ Cm){
  __shared__ float inT[32*129];   // [d][e], e<128, pad 129
  __shared__ float xpT[64*35];    // [e][j], j<34, pad 35
  __shared__ float xl[2][4][32];
  __shared__ float xh[2][4][64];
  int tid = threadIdx.x;
  for (int i = tid; i < 128*32; i += 256){
    int e = i >> 5, d = i & 31;
    inT[d*129 + e] = inw[i];
  }
  for (int i = tid; i < 34*64; i += 256){
    int j = i >> 6, e = i & 63;
    xpT[e*35 + j] = xpw[i];
  }
  int w = tid >> 6, lane = tid & 63;
  for (int rg = 0; rg < 32; rg++){
    int p = rg & 1;
    int r = (blockIdx.x*32 + rg)*4 + w;       // r = node*256 + l
    if (lane < 32) xl[p][w][lane] = xin[r*32 + lane];
    __syncthreads();
    float a0 = 0.f, a1 = 0.f;
    #pragma unroll
    for (int d = 0; d < 32; d++){
      float xv = xl[p][w][d];
      a0 = fmaf(inT[d*129 + lane], xv, a0);
      a1 = fmaf(inT[d*129 + 64 + lane], xv, a1);
    }
    int node = r >> 8, l = r & 255;
    long ob = (long)l*NN_ + node;             // t-major layout
    u[ob*64 + lane] = f2b(a0);
    zs[ob*64 + lane] = f2b(a1 / (1.f + expf(-a1)));
    xh[p][w][lane] = a0;
    __syncthreads();
    if (lane < 34){
      float acc = 0.f;
      #pragma unroll
      for (int e = 0; e < 64; e++) acc = fmaf(xpT[e*35 + lane], xh[p][w][e], acc);
      if (lane < 2)       dtr[ob*2 + lane] = acc;
      else if (lane < 18) Bm[ob*16 + lane - 2] = f2b(acc);
      else                Cm[ob*16 + lane - 18] = f2b(acc);
    }
  }
}

// ---------- k_ub: uBsp = gcn_vec(u_t,gB)*sp and spb = sp = softplus(dt) ----------
// 8 t's per block (weights amortized); guard-free 19->20 padding as R6.
__global__ __launch_bounds__(256)
void k_ub(const bf16* __restrict__ u, const float* __restrict__ gBw,
          const float* __restrict__ gBb, const float* __restrict__ Mg,
          const float* __restrict__ dtrg, const float* __restrict__ dtw,
          const float* __restrict__ dtb,
          bf16* __restrict__ uBsp, bf16* __restrict__ spb){
  __shared__ float wT[64*65];     // [d][e] pad 65
  __shared__ float uL[19*64];
  __shared__ float hL[20*64];
  __shared__ float MLP[640];      // [vp][vg*8+k] = M_pad[vg+4k][vp]
  int b = blockIdx.x & 31, tc = blockIdx.x >> 5;
  int tid = threadIdx.x;
  for (int i = tid; i < 4096; i += 256){
    int e = i >> 6, d = i & 63;
    wT[d*65 + e] = gBw[i];
  }
  for (int i = tid; i < 640; i += 256){
    int vp = i >> 5, c = i & 31, g = c >> 3, k = c & 7;
    int v = g + 4*k;
    MLP[i] = (k < 5 && vp < 19 && v < 19) ? Mg[b*361 + v*19 + vp] : 0.f;
  }
  int vg = tid >> 6, e = tid & 63;
  int v0 = vg, v1 = vg+4, v2 = vg+8, v3 = vg+12, v4 = vg+16;
  int v4c = (vg == 3) ? 18 : v4;
  float w0e = dtw[e*2], w1e = dtw[e*2 + 1], dbe = dtb[e], bbe = gBb[e];
  const float* mlb = MLP + vg*8;
  for (int tt = 0; tt < 8; tt++){
    int t = tc*8 + tt;
    long rb = (long)t*NN_ + b*19;
    const bf16* up = u + rb*64;
    for (int i = tid; i < 1216; i += 256) uL[i] = b2f(up[i]);
    __syncthreads();
    float h0=0.f,h1=0.f,h2=0.f,h3=0.f,h4=0.f;
    #pragma unroll
    for (int d = 0; d < 64; d++){
      float wv = wT[d*65 + e];
      h0 = fmaf(wv, uL[v0*64 + d], h0);
      h1 = fmaf(wv, uL[v1*64 + d], h1);
      h2 = fmaf(wv, uL[v2*64 + d], h2);
      h3 = fmaf(wv, uL[v3*64 + d], h3);
      h4 = fmaf(wv, uL[v4c*64 + d], h4);
    }
    hL[v0*64 + e] = h0; hL[v1*64 + e] = h1; hL[v2*64 + e] = h2;
    hL[v3*64 + e] = h3; hL[v4*64 + e] = h4;
    __syncthreads();
    float acc0=bbe, acc1=bbe, acc2=bbe, acc3=bbe, acc4=bbe;
    #pragma unroll
    for (int vp = 0; vp < 20; vp++){
      float hv = hL[vp*64 + e];
      float4 m4 = *(const float4*)(mlb + vp*32);
      float  m5 = mlb[vp*32 + 4];
      acc0 = fmaf(m4.x, hv, acc0); acc1 = fmaf(m4.y, hv, acc1);
      acc2 = fmaf(m4.z, hv, acc2); acc3 = fmaf(m4.w, hv, acc3);
      acc4 = fmaf(m5,  hv, acc4);
    }
    float2 q0 = *(const float2*)(dtrg + (rb+v0)*2);
    float2 q1 = *(const float2*)(dtrg + (rb+v1)*2);
    float2 q2 = *(const float2*)(dtrg + (rb+v2)*2);
    float2 q3 = *(const float2*)(dtrg + (rb+v3)*2);
    float2 q4 = *(const float2*)(dtrg + (rb+v4c)*2);
    float s0 = softplusf(fmaf(q0.x, w0e, fmaf(q0.y, w1e, dbe)));
    float s1 = softplusf(fmaf(q1.x, w0e, fmaf(q1.y, w1e, dbe)));
    float s2 = softplusf(fmaf(q2.x, w0e, fmaf(q2.y, w1e, dbe)));
    float s3 = softplusf(fmaf(q3.x, w0e, fmaf(q3.y, w1e, dbe)));
    float s4 = softplusf(fmaf(q4.x, w0e, fmaf(q4.y, w1e, dbe)));
    bf16* op = uBsp + rb*64;
    bf16* sp = spb + rb*64;
    op[v0*64 + e] = f2b(acc0*s0);  sp[v0*64 + e] = f2b(s0);
    op[v1*64 + e] = f2b(acc1*s1);  sp[v1*64 + e] = f2b(s1);
    op[v2*64 + e] = f2b(acc2*s2);  sp[v2*64 + e] = f2b(s2);
    op[v3*64 + e] = f2b(acc3*s3);  sp[v3*64 + e] = f2b(s3);
    if (vg != 3){ op[v4*64 + e] = f2b(acc4*s4); sp[v4*64 + e] = f2b(s4); }
    __syncthreads();
  }
}

// ---------- MFMA scan v3: 2 barriers/step, shared phase A-frags ----------
// Part1(t): aggA(t) H0->S, aggC(t-1) H1->y (Yx parity dbuf), store yp(t-2),
//           prefetch globals(t+1).   barrier
// Part2(t): ONE S A-frag read feeds BOTH Wc (->H1(t)) and Wa (->H0(t+1)). barrier
__global__ __launch_bounds__(1024)
void k_scan(const float* __restrict__ Mg,
            const bf16* __restrict__ spbg, const bf16* __restrict__ uBspg,
            const bf16* __restrict__ Bg, const bf16* __restrict__ Cg,
            const float* __restrict__ gAw, const float* __restrict__ gAb,
            const float* __restrict__ gCw, const float* __restrict__ gCb,
            const float* __restrict__ Alog, bf16* __restrict__ yp)
{
  __shared__ __align__(16) short Sb[2*32*72];
  __shared__ __align__(16) short H0[2*64*40];
  __shared__ __align__(16) short H1[2*64*40];
  __shared__ __align__(16) short Yx[2][32*64];
  int b = blockIdx.x >> 3, npair = blockIdx.x & 7;
  int tid = threadIdx.x;
  int team = tid >> 9;
  int tw   = (tid >> 6) & 7;
  int lane = tid & 63;
  int l15  = lane & 15, quad = lane >> 4;
  int n = npair*2 + team;
  int mt = tw >> 2, nt = tw & 3;        // phase roles
  int et = tw >> 1, vt = tw & 1;        // agg roles

  for (int i = tid; i < 2304; i += 1024) ((int*)Sb)[i] = 0;

  // phase B-frags (Wa^T / Wc^T)
  bf16x8 wa0, wa1, wc0, wc1;
  {
    #define PACK8(dst, p) { float4 lo_ = *(const float4*)(p); \
      float4 hi_ = *(const float4*)((p)+4); \
      dst[0]=(short)f2bs(lo_.x); dst[1]=(short)f2bs(lo_.y); \
      dst[2]=(short)f2bs(lo_.z); dst[3]=(short)f2bs(lo_.w); \
      dst[4]=(short)f2bs(hi_.x); dst[5]=(short)f2bs(hi_.y); \
      dst[6]=(short)f2bs(hi_.z); dst[7]=(short)f2bs(hi_.w); }
    const float* wrA = gAw + (16*nt + l15)*64 + quad*8;
    const float* wrC = gCw + (16*nt + l15)*64 + quad*8;
    PACK8(wa0, wrA) PACK8(wa1, wrA + 32)
    PACK8(wc0, wrC) PACK8(wc1, wrC + 32)
    #undef PACK8
  }
  // agg B-frag (M^T), zero-padded in k (vp>=19)
  bf16x8 mf;
  {
    const float* mb = Mg + b*361;
    int vr = 16*vt + l15; if (vr > 18) vr = 18;
    #pragma unroll
    for (int j = 0; j < 8; j++){
      int vp = quad*8 + j;
      mf[j] = (short)f2bs((vp < 19) ? mb[vr*19 + vp] : 0.f);
    }
  }
  int e0 = 16*et + 4*quad;
  int v_ = 16*vt + l15;
  int vc = (v_ > 18) ? 18 : v_;
  bool vok = (v_ < 19);
  float4 gab = *(const float4*)(gAb + e0);
  float4 gcb = *(const float4*)(gCb + e0);
  float An0 = -__expf(Alog[(e0+0)*16 + n]);
  float An1 = -__expf(Alog[(e0+1)*16 + n]);
  float An2 = -__expf(Alog[(e0+2)*16 + n]);
  float An3 = -__expf(Alog[(e0+3)*16 + n]);

  short* Sme  = Sb + team*32*72;
  short* H0me = H0 + team*64*40;
  short* H1me = H1 + team*64*40;
  int nodeBase = b*19;
  const short* prS  = Sme + (16*mt + l15)*72 + quad*8;
  short*       pwH0 = H0me + (16*nt + l15)*40 + 16*mt + quad*4;
  short*       pwH1 = H1me + (16*nt + l15)*40 + 16*mt + quad*4;
  const short* arH0 = H0me + (16*et + l15)*40 + quad*8;
  const short* arH1 = H1me + (16*et + l15)*40 + quad*8;
  short*       swS  = Sme + v_*72 + e0;

  // rolling global pointers (t = 0)
  long row0 = (long)nodeBase + vc;
  const ushort_t* psp = (const ushort_t*)spbg  + row0*64 + e0;
  const ushort_t* pub = (const ushort_t*)uBspg + row0*64 + e0;
  const ushort_t* pB  = (const ushort_t*)Bg + row0*16 + n;
  const ushort_t* pC  = (const ushort_t*)Cg + row0*16 + n;
  uint2 sp_n = *(const uint2*)psp;
  uint2 ub_n = *(const uint2*)pub;
  float B_n = busf(*pB);
  float C_b2 = busf(*pC);          // C(t) buffer
  float C_a = 0.f;                 // C(t-1)
  float pyo0=0.f,pyo1=0.f,pyo2=0.f,pyo3=0.f;   // y(t-2) (team0)
  float pyn0=0.f,pyn1=0.f,pyn2=0.f,pyn3=0.f;   // y(t-1) (team0)

  __syncthreads();
  // prologue phase A(0): S zeros -> H0(0) zeros (via MFMA for layout fidelity)
  {
    bf16x8 a0 = *(const bf16x8*)prS;
    bf16x8 a1 = *(const bf16x8*)(prS + 32);
    f32x4 p = {0.f,0.f,0.f,0.f};
    p = __builtin_amdgcn_mfma_f32_16x16x32_bf16(a0, wa0, p, 0,0,0);
    p = __builtin_amdgcn_mfma_f32_16x16x32_bf16(a1, wa1, p, 0,0,0);
    uint2 h; h.x = pkrn(p[0], p[1]); h.y = pkrn(p[2], p[3]);
    *(uint2*)pwH0 = h;
  }
  __syncthreads();

  for (int t = 0; t < 256; t++){
    // ---- Part1 ----
    uint2 sp_u = sp_n, ub_u = ub_n; float B_u = B_n;
    psp += NN_*64; pub += NN_*64; pB += NN_*16; pC += NN_*16;
    sp_n = *(const uint2*)psp;
    ub_n = *(const uint2*)pub;
    B_n = busf(*pB);
    float C_t = busf(*pC);
    bf16x8 hf0 = *(const bf16x8*)arH0;
    bf16x8 hf1 = *(const bf16x8*)arH1;
    // aggA(t): state update
    {
      f32x4 qa = {gab.x, gab.y, gab.z, gab.w};
      qa = __builtin_amdgcn_mfma_f32_16x16x32_bf16(hf0, mf, qa, 0,0,0);
      float dA0 = __expf(blo(sp_u.x)*An0);
      float dA1 = __expf(bhi(sp_u.x)*An1);
      float dA2 = __expf(blo(sp_u.y)*An2);
      float dA3 = __expf(bhi(sp_u.y)*An3);
      float x0 = fmaf(qa[0], dA0, blo(ub_u.x)*B_u);
      float x1 = fmaf(qa[1], dA1, bhi(ub_u.x)*B_u);
      float x2 = fmaf(qa[2], dA2, blo(ub_u.y)*B_u);
      float x3 = fmaf(qa[3], dA3, bhi(ub_u.y)*B_u);
      uint2 sv; sv.x = pkrn(x0, x1); sv.y = pkrn(x2, x3);
      *(uint2*)swS = sv;     // pad rows (v_>=19) get finite garbage; zeroed by mf in agg k-dim
    }
    // store yp(t-2) (team0)
    if (team == 0 && t >= 2 && vok){
      uint2 yv = *(const uint2*)(&Yx[t & 1][v_*64 + e0]);
      uint2 ov;
      ov.x = pkrn(pyo0 + blo(yv.x), pyo1 + bhi(yv.x));
      ov.y = pkrn(pyo2 + blo(yv.y), pyo3 + bhi(yv.y));
      *(uint2*)(yp + (((long)npair*256 + (t-2))*NN_ + nodeBase + v_)*64 + e0) = ov;
    }
    // aggC(t-1): y
    if (t >= 1){
      f32x4 qc = {gcb.x, gcb.y, gcb.z, gcb.w};
      qc = __builtin_amdgcn_mfma_f32_16x16x32_bf16(hf1, mf, qc, 0,0,0);
      float y0 = qc[0]*C_a, y1 = qc[1]*C_a, y2 = qc[2]*C_a, y3 = qc[3]*C_a;
      if (team == 1){
        uint2 yv; yv.x = pkrn(y0, y1); yv.y = pkrn(y2, y3);
        *(uint2*)(&Yx[(t-1) & 1][v_*64 + e0]) = yv;
      } else {
        pyo0 = pyn0; pyo1 = pyn1; pyo2 = pyn2; pyo3 = pyn3;
        pyn0 = y0; pyn1 = y1; pyn2 = y2; pyn3 = y3;
      }
    }
    C_a = C_b2; C_b2 = C_t;
    __syncthreads();
    // ---- Part2: phaseC(t) and phaseA(t+1), one A-frag read ----
    {
      bf16x8 a0 = *(const bf16x8*)prS;
      bf16x8 a1 = *(const bf16x8*)(prS + 32);
      f32x4 p = {0.f,0.f,0.f,0.f};
      p = __builtin_amdgcn_mfma_f32_16x16x32_bf16(a0, wc0, p, 0,0,0);
      p = __builtin_amdgcn_mfma_f32_16x16x32_bf16(a1, wc1, p, 0,0,0);
      uint2 h; h.x = pkrn(p[0], p[1]); h.y = pkrn(p[2], p[3]);
      *(uint2*)pwH1 = h;
      f32x4 r = {0.f,0.f,0.f,0.f};
      r = __builtin_amdgcn_mfma_f32_16x16x32_bf16(a0, wa0, r, 0,0,0);
      r = __builtin_amdgcn_mfma_f32_16x16x32_bf16(a1, wa1, r, 0,0,0);
      uint2 g; g.x = pkrn(r[0], r[1]); g.y = pkrn(r[2], r[3]);
      *(uint2*)pwH0 = g;
    }
    __syncthreads();
  }
  // epilogue: aggC(255), then stores for t=254, 255
  {
    bf16x8 hf1 = *(const bf16x8*)arH1;
    f32x4 qc = {gcb.x, gcb.y, gcb.z, gcb.w};
    qc = __builtin_amdgcn_mfma_f32_16x16x32_bf16(hf1, mf, qc, 0,0,0);
    float y0 = qc[0]*C_a, y1 = qc[1]*C_a, y2 = qc[2]*C_a, y3 = qc[3]*C_a;
    if (team == 1){
      uint2 yv; yv.x = pkrn(y0, y1); yv.y = pkrn(y2, y3);
      *(uint2*)(&Yx[1][v_*64 + e0]) = yv;
    } else {
      pyo0 = pyn0; pyo1 = pyn1; pyo2 = pyn2; pyo3 = pyn3;
      pyn0 = y0; pyn1 = y1; pyn2 = y2; pyn3 = y3;
    }
  }
  __syncthreads();
  if (team == 0 && vok){
    uint2 yv = *(const uint2*)(&Yx[0][v_*64 + e0]);     // y(254) from team1
    uint2 ov;
    ov.x = pkrn(pyo0 + blo(yv.x), pyo1 + bhi(yv.x));
    ov.y = pkrn(pyo2 + blo(yv.y), pyo3 + bhi(yv.y));
    *(uint2*)(yp + (((long)npair*256 + 254)*NN_ + nodeBase + v_)*64 + e0) = ov;
    uint2 yw = *(const uint2*)(&Yx[1][v_*64 + e0]);     // y(255)
    uint2 o2;
    o2.x = pkrn(pyn0 + blo(yw.x), pyn1 + bhi(yw.x));
    o2.y = pkrn(pyn2 + blo(yw.y), pyn3 + bhi(yw.y));
    *(uint2*)(yp + (((long)npair*256 + 255)*NN_ + nodeBase + v_)*64 + e0) = o2;
  }
}

// ---------- reduce partials, gate, out_proj (16 row-groups/block) ----------
__global__ __launch_bounds__(256)
void k_final(const bf16* __restrict__ yp, const bf16* __restrict__ u,
             const bf16* __restrict__ zs, const float* __restrict__ Dp,
             const float* __restrict__ ow, float* __restrict__ out)
{
  __shared__ float oT[64*33];   // [e][o] pad 33
  __shared__ float yl[2][4][64];
  int tid = threadIdx.x;
  for (int i = tid; i < 32*64; i += 256){
    int o = i >> 6, e = i & 63;
    oT[e*33 + o] = ow[i];
  }
  int w = tid >> 6, lane = tid & 63;
  float dpl = Dp[lane];
  for (int rg = 0; rg < 16; rg++){
    int p = rg & 1;
    long r = (long)(blockIdx.x*16 + rg)*4 + w;    // r = t*608 + node
    long base = r*64;
    float y = dpl * b2f(u[base + lane]);
    #pragma unroll
    for (int q = 0; q < 8; q++) y += b2f(yp[(long)q*NTOT + base + lane]);
    y *= b2f(zs[base + lane]);
    yl[p][w][lane] = y;
    __syncthreads();
    if (lane < 32){
      float acc = 0.f;
      #pragma unroll
      for (int e = 0; e < 64; e++) acc = fmaf(oT[e*33 + lane], yl[p][w][e], acc);
      int t = (int)(r / NN_), node = (int)(r - (long)t*NN_);
      out[((long)node*256 + t)*32 + lane] = acc;
    }
  }
}

extern "C" void kernel_launch(void* const* d_in, const int* in_sizes, int n_in,
                              void* d_out, int out_size, void* d_ws, size_t ws_size,
                              hipStream_t stream)
{
  (void)in_sizes; (void)n_in; (void)out_size; (void)ws_size;
  const float* xin = (const float*)d_in[0];
  const int*   ei  = (const int*)  d_in[1];
  const float* ew  = (const float*)d_in[2];
  const float* inw = (const float*)d_in[3];
  const float* xpw = (const float*)d_in[4];
  const float* dtw = (const float*)d_in[5];
  const float* dtb = (const float*)d_in[6];
  const float* Alog= (const float*)d_in[7];
  const float* Dp  = (const float*)d_in[8];
  const float* ow  = (const float*)d_in[9];
  const float* gAw = (const float*)d_in[10];
  const float* gAb = (const float*)d_in[11];
  const float* gBw = (const float*)d_in[12];
  const float* gBb = (const float*)d_in[13];
  const float* gCw = (const float*)d_in[14];
  const float* gCb = (const float*)d_in[15];
  float* out = (float*)d_out;

  float* Mg   = (float*)d_ws;            // 11552 f32
  float* deg  = Mg + 11552;              // 608
  float* dinv = deg + 608;               // 608
  float* dtr  = dinv + 608;              // 2*NROWS f32
  bf16*  u    = (bf16*)(dtr + 2*NROWS);  // NTOT bf16
  bf16*  zs   = u + NTOT;
  bf16*  uBsp = zs + NTOT;
  bf16*  Bm   = uBsp + NTOT;             // NBC
  bf16*  Cm   = Bm + NBC;                // NBC
  bf16*  spb  = Cm + NBC;                // NTOT
  bf16*  yp   = spb + NTOT;              // 8*NTOT  (total ws ~250 MB)

  hipMemsetAsync(d_ws, 0, (11552 + 608)*sizeof(float), stream);  // M + deg
  k_deg  <<<(NE_ + 255)/256, 256, 0, stream>>>(ei, ew, deg);
  k_dinv <<<(NN_ + 255)/256, 256, 0, stream>>>(deg, dinv, Mg);
  k_edges<<<(NE_ + 255)/256, 256, 0, stream>>>(ei, ew, dinv, Mg);
  k_proj <<<NROWS/(4*32), 256, 0, stream>>>(xin, inw, xpw, u, zs, dtr, Bm, Cm);
  k_ub   <<<32*32, 256, 0, stream>>>(u, gBw, gBb, Mg, dtr, dtw, dtb, uBsp, spb);
  k_scan <<<NB_*8, 1024, 0, stream>>>(Mg, spb, uBsp, Bm, Cm, gAw, gAb, gCw, gCb,
                                      Alog, yp);
  k_final<<<NROWS/(4*16), 256, 0, stream>>>(yp, u, zs, Dp, ow, out);
}